// Round 6
// baseline (683.783 us; speedup 1.0000x reference)
//
#include <hip/hip_runtime.h>

// ---------------- problem constants ----------------
#define Q_   25600
#define C_   256
#define NH_  8
#define HD_  32
#define NP_  4
#define LC_  2
#define HW_  160          // H == W == 160

#define QC   (Q_ * C_)            // 6,553,600
#define VC   (2 * QC)             // 13,107,200
#define REFN (Q_ * LC_ * 2)       // 102,400

typedef unsigned short ushort_t;
typedef __attribute__((ext_vector_type(8))) short short8;
typedef __attribute__((ext_vector_type(4))) float f32x4;

// ---------------- bf16 helpers ----------------
__device__ __forceinline__ float b2f(ushort_t u) {
    union { unsigned int u32; float f; } c; c.u32 = ((unsigned int)u) << 16; return c.f;
}
__device__ __forceinline__ ushort_t f2b(float f) {
    union { float f; unsigned int u32; } c; c.f = f;
    unsigned int u = c.u32;
    return (ushort_t)((u + 0x7FFFu + ((u >> 16) & 1u)) >> 16);
}
__device__ __forceinline__ unsigned int pack2(float lo, float hi){
    return (unsigned int)f2b(lo) | ((unsigned int)f2b(hi) << 16);
}
__device__ __forceinline__ short8 pack8(float4 a, float4 b){
    union { short8 s; ushort_t u[8]; } r;
    r.u[0]=f2b(a.x); r.u[1]=f2b(a.y); r.u[2]=f2b(a.z); r.u[3]=f2b(a.w);
    r.u[4]=f2b(b.x); r.u[5]=f2b(b.y); r.u[6]=f2b(b.z); r.u[7]=f2b(b.w);
    return r.s;
}
__device__ __forceinline__ float uasf(unsigned int u){
    union { unsigned int u32; float f; } c; c.u32 = u; return c.f;
}
// unpack 4 bf16 (packed in uint2) -> 4 floats
__device__ __forceinline__ float4 unpk4(uint2 u){
    float4 r;
    r.x = uasf(u.x << 16); r.y = uasf(u.x & 0xFFFF0000u);
    r.z = uasf(u.y << 16); r.w = uasf(u.y & 0xFFFF0000u);
    return r;
}

// ---------------- prologue: qpq = bf16(query+qpos) + weight transposes (fp32->bf16) ----------------
struct TDesc { const float* src; ushort_t* dst; int K; int N; };
struct TAll  { TDesc t[10]; };

#define QC4   (QC / 4)        // 1,638,400
#define TRANS_TOTAL 860160
#define PRO_TOTAL (QC4 + TRANS_TOTAL)

__global__ __launch_bounds__(256) void prologue_kernel(
    const float* __restrict__ query, const float* __restrict__ qpos,
    ushort_t* __restrict__ qpq, TAll td)
{
    int i = blockIdx.x * 256 + threadIdx.x;
    if (i < QC4) {
        float4 qv = ((const float4*)query)[i];
        float4 pv = ((const float4*)qpos)[i];
        uint2 o;
        o.x = pack2(qv.x + pv.x, qv.y + pv.y);
        o.y = pack2(qv.z + pv.z, qv.w + pv.w);
        ((uint2*)qpq)[i] = o;
        return;
    }
    i -= QC4;
    #pragma unroll 1
    for (int m = 0; m < 10; m++) {
        int sz = td.t[m].K * td.t[m].N;
        if (i < sz) {
            int N = td.t[m].N, K = td.t[m].K;
            int k = i / N, n = i - k * N;
            td.t[m].dst[(size_t)n * K + k] = f2b(td.t[m].src[i]);
            return;
        }
        i -= sz;
    }
}

// ---------------- tiny: spatial_shapes int32 -> fp32 ----------------
__global__ void ss_kernel(const int* __restrict__ ss, float* __restrict__ out_ss)
{
    int i = threadIdx.x;
    if (i < 4) out_ss[i] = (float)ss[i];
}

// ---------------- MFMA GEMM ----------------
// C = A[M,K] @ B[K,N] + bias (+res) (+relu).  Bt = B^T [N,K] bf16.
// Per-wave tile 32x(16*WN); block = 4 waves stacked in M -> 128 rows/block.
// (32-row wave tile doubles wave count vs 64-row: occupancy lever for the
//  latency-bound small-N GEMMs; compiler handles load/MFMA interleave.)
// AF32: A operand read from fp32 (converted to bf16 fragments on the fly).
// RESM: 0 none, 1 bf16 residual, 2 fp32 residual.
// VOUT: write head-major value layout [(col>>5)*M + row][32] instead of [row][N].
template<int WN, bool RELU, int RESM, bool AF32, bool VOUT>
__global__ __launch_bounds__(256) void gemm_bf16(
    const ushort_t* __restrict__ A16, const float* __restrict__ A32,
    const ushort_t* __restrict__ Bt, const float* __restrict__ bias,
    const ushort_t* __restrict__ res16, const float* __restrict__ res32,
    ushort_t* __restrict__ Cout, int M, int N, int K)
{
    const int lane = threadIdx.x & 63;
    const int wave = threadIdx.x >> 6;
    const int m0 = blockIdx.x * 128 + wave * 32;
    const int n0 = blockIdx.y * (16 * WN);
    const int r = lane & 15, quad = lane >> 4;

    f32x4 acc[2][WN];
    #pragma unroll
    for (int i = 0; i < 2; i++)
        #pragma unroll
        for (int j = 0; j < WN; j++) acc[i][j] = (f32x4){0.f, 0.f, 0.f, 0.f};

    const ushort_t* Ab16 = AF32 ? nullptr : (A16 + (size_t)(m0 + r) * K + quad * 8);
    const float*    Ab32 = AF32 ? (A32 + (size_t)(m0 + r) * K + quad * 8) : nullptr;
    const ushort_t* Bbase = Bt + (size_t)(n0 + r) * K + quad * 8;

    for (int k0 = 0; k0 < K; k0 += 32) {
        short8 af[2], bfr[WN];
        #pragma unroll
        for (int i = 0; i < 2; i++) {
            if (AF32) {
                float4 u = *(const float4*)(Ab32 + (size_t)i * 16 * K + k0);
                float4 v = *(const float4*)(Ab32 + (size_t)i * 16 * K + k0 + 4);
                af[i] = pack8(u, v);
            } else {
                af[i] = *(const short8*)(Ab16 + (size_t)i * 16 * K + k0);
            }
        }
        #pragma unroll
        for (int j = 0; j < WN; j++)
            bfr[j] = *(const short8*)(Bbase + (size_t)j * 16 * K + k0);
        #pragma unroll
        for (int i = 0; i < 2; i++)
            #pragma unroll
            for (int j = 0; j < WN; j++)
                acc[i][j] = __builtin_amdgcn_mfma_f32_16x16x32_bf16(af[i], bfr[j], acc[i][j], 0, 0, 0);
    }

    float bv[WN];
    #pragma unroll
    for (int j = 0; j < WN; j++) bv[j] = bias[n0 + j * 16 + r];

    #pragma unroll
    for (int i = 0; i < 2; i++) {
        int row = m0 + i * 16 + quad * 4;
        #pragma unroll
        for (int j = 0; j < WN; j++) {
            int col = n0 + j * 16 + r;
            #pragma unroll
            for (int t = 0; t < 4; t++) {
                float v = acc[i][j][t] + bv[j];
                if (RESM == 1) v += b2f(res16[(size_t)(row + t) * N + col]);
                if (RESM == 2) v += res32[(size_t)(row + t) * N + col];
                if (RELU) v = fmaxf(v, 0.f);
                if (VOUT) {
                    // head-major: [(head)*M + row][32]; head = col>>5, ch = col&31
                    Cout[((size_t)(col >> 5) * (size_t)M + (size_t)(row + t)) * HD_ + (col & 31)] = f2b(v);
                } else {
                    Cout[(size_t)(row + t) * N + col] = f2b(v);
                }
            }
        }
    }
}

// ---------------- fused softmax + bilinear sampling ----------------
// v layout: [(h*L + l)*Q + pix][HD]  (head-major, 64 B per pixel record)
// 8 lanes per (q,h) group; each lane owns 4 channels (uint2 corner loads).
template<int L>
__global__ __launch_bounds__(256) void sample_kernel(
    const ushort_t* __restrict__ v,    // head-major projected value (bf16)
    const ushort_t* __restrict__ off,  // [Q, NH*L*NP*2] (bf16)
    const ushort_t* __restrict__ aw,   // [Q, NH*L*NP] raw logits (bf16)
    const float*    __restrict__ ref,  // [Q, LC, 2] fp32
    ushort_t* __restrict__ outp)       // [Q, C] bf16
{
    const int t   = blockIdx.x * 256 + threadIdx.x;
    const int g   = t >> 3;            // (q,h) group
    const int sub = t & 7;             // 4-channel slice within head
    const int q   = g >> 3;
    const int h   = g & 7;
    const int P   = L * NP_;

    // ---- softmax over P logits (vectorized bf16 load, normalized in-place) ----
    float w[2 * NP_];
    {
        union { uint4 q4; uint2 q2; ushort_t u[8]; } ab;
        const ushort_t* awp = aw + (size_t)q * (NH_ * P) + h * P;
        if (L == 2) ab.q4 = *(const uint4*)awp;
        else        ab.q2 = *(const uint2*)awp;
        float mx = -1e30f;
        #pragma unroll
        for (int i = 0; i < P; i++) { w[i] = b2f(ab.u[i]); mx = fmaxf(mx, w[i]); }
        float s = 0.f;
        #pragma unroll
        for (int i = 0; i < P; i++) { w[i] = __expf(w[i] - mx); s += w[i]; }
        float inv = 1.f / s;
        #pragma unroll
        for (int i = 0; i < P; i++) w[i] *= inv;
    }

    // ---- offsets (vectorized bf16 load) ----
    float offx[2 * NP_], offy[2 * NP_];
    {
        union { uint4 q4[2]; ushort_t u[16]; } ob;
        const ushort_t* offp = off + (size_t)q * (NH_ * P * 2) + h * (P * 2);
        ob.q4[0] = *(const uint4*)offp;
        if (L == 2) ob.q4[1] = *(const uint4*)(offp + 8);
        #pragma unroll
        for (int i = 0; i < P; i++) { offx[i] = b2f(ob.u[2 * i]); offy[i] = b2f(ob.u[2 * i + 1]); }
    }

    const ushort_t* vh = v + ((size_t)(h * L) * Q_) * HD_ + sub * 4;
    float4 acc = {0.f, 0.f, 0.f, 0.f};

    #pragma unroll
    for (int l = 0; l < L; l++) {
        float rx = ref[((size_t)q * LC_ + l) * 2 + 0] * (float)HW_ - 0.5f;
        float ry = ref[((size_t)q * LC_ + l) * 2 + 1] * (float)HW_ - 0.5f;
        const ushort_t* vl = vh + (size_t)l * ((size_t)Q_ * HD_);
        #pragma unroll
        for (int p = 0; p < NP_; p++) {
            const int ip = l * NP_ + p;
            float x = rx + offx[ip];
            float y = ry + offy[ip];
            x = fminf(fmaxf(x, -1e4f), 1e4f);
            y = fminf(fmaxf(y, -1e4f), 1e4f);
            float xf = floorf(x), yf = floorf(y);
            float tx = x - xf, ty = y - yf;
            int x0 = (int)xf, y0 = (int)yf;
            int x1 = x0 + 1, y1 = y0 + 1;
            int xc0 = min(max(x0, 0), HW_ - 1), xc1 = min(max(x1, 0), HW_ - 1);
            int yc0 = min(max(y0, 0), HW_ - 1), yc1 = min(max(y1, 0), HW_ - 1);
            bool vx0 = (unsigned)x0 < (unsigned)HW_, vx1 = (unsigned)x1 < (unsigned)HW_;
            bool vy0 = (unsigned)y0 < (unsigned)HW_, vy1 = (unsigned)y1 < (unsigned)HW_;

            // fold attention weight + validity into the 4 corner weights
            float aww = w[ip];
            float w00 = (1.f - tx) * (1.f - ty) * aww;
            float w10 = tx * (1.f - ty) * aww;
            float w01 = (1.f - tx) * ty * aww;
            float w11 = tx * ty * aww;
            w00 = (vx0 & vy0) ? w00 : 0.f;
            w10 = (vx1 & vy0) ? w10 : 0.f;
            w01 = (vx0 & vy1) ? w01 : 0.f;
            w11 = (vx1 & vy1) ? w11 : 0.f;

            int r0 = yc0 * HW_, r1 = yc1 * HW_;
            uint2 u00 = *(const uint2*)(vl + (size_t)(r0 + xc0) * HD_);
            uint2 u10 = *(const uint2*)(vl + (size_t)(r0 + xc1) * HD_);
            uint2 u01 = *(const uint2*)(vl + (size_t)(r1 + xc0) * HD_);
            uint2 u11 = *(const uint2*)(vl + (size_t)(r1 + xc1) * HD_);
            float4 c00 = unpk4(u00), c10 = unpk4(u10), c01 = unpk4(u01), c11 = unpk4(u11);

            acc.x += c00.x * w00 + c10.x * w10 + c01.x * w01 + c11.x * w11;
            acc.y += c00.y * w00 + c10.y * w10 + c01.y * w01 + c11.y * w11;
            acc.z += c00.z * w00 + c10.z * w10 + c01.z * w01 + c11.z * w11;
            acc.w += c00.w * w00 + c10.w * w10 + c01.w * w01 + c11.w * w11;
        }
    }

    uint2 o;
    o.x = pack2(acc.x, acc.y);
    o.y = pack2(acc.z, acc.w);
    *(uint2*)(outp + (size_t)q * C_ + h * HD_ + sub * 4) = o;
}

// ---------------- LayerNorm (wave per row of 256) ----------------
// x bf16; gamma/beta fp32. OUT32: y32 fp32 out, else y16 bf16 out.
// optional y2 (bf16) = y + qpos (qpos fp32).
template<bool OUT32>
__global__ __launch_bounds__(256) void ln_kernel(
    const ushort_t* __restrict__ x, const float* __restrict__ g,
    const float* __restrict__ b, ushort_t* __restrict__ y16,
    float* __restrict__ y32,
    const float* __restrict__ qpos, ushort_t* __restrict__ y2)
{
    const int lane = threadIdx.x & 63;
    const int wave = threadIdx.x >> 6;
    const size_t row = (size_t)blockIdx.x * 4 + wave;
    const size_t base = row * C_ + lane * 4;

    uint2 xv = *(const uint2*)(x + base);
    float f0 = b2f((ushort_t)(xv.x & 0xFFFF)), f1 = b2f((ushort_t)(xv.x >> 16));
    float f2 = b2f((ushort_t)(xv.y & 0xFFFF)), f3 = b2f((ushort_t)(xv.y >> 16));
    float s  = f0 + f1 + f2 + f3;
    float sq = f0 * f0 + f1 * f1 + f2 * f2 + f3 * f3;
    #pragma unroll
    for (int m = 1; m < 64; m <<= 1) { s += __shfl_xor(s, m, 64); sq += __shfl_xor(sq, m, 64); }
    float mean = s * (1.f / 256.f);
    float var  = sq * (1.f / 256.f) - mean * mean;
    float rinv = rsqrtf(fmaxf(var, 0.f) + 1e-5f);

    float4 gv = *(const float4*)(g + lane * 4);
    float4 bv = *(const float4*)(b + lane * 4);
    float o0 = (f0 - mean) * rinv * gv.x + bv.x;
    float o1 = (f1 - mean) * rinv * gv.y + bv.y;
    float o2 = (f2 - mean) * rinv * gv.z + bv.z;
    float o3 = (f3 - mean) * rinv * gv.w + bv.w;

    if (OUT32) {
        float4 o; o.x = o0; o.y = o1; o.z = o2; o.w = o3;
        *(float4*)(y32 + base) = o;
    } else {
        uint2 ov; ov.x = pack2(o0, o1); ov.y = pack2(o2, o3);
        *(uint2*)(y16 + base) = ov;
    }

    if (y2) {
        float4 pv = *(const float4*)(qpos + base);
        uint2 o2v;
        o2v.x = pack2(o0 + pv.x, o1 + pv.y);
        o2v.y = pack2(o2 + pv.z, o3 + pv.w);
        *(uint2*)(y2 + base) = o2v;
    }
}

// ---------------- host ----------------
extern "C" void kernel_launch(void* const* d_in, const int* in_sizes, int n_in,
                              void* d_out, int out_size, void* d_ws, size_t ws_size,
                              hipStream_t stream)
{
    const float* query = (const float*)d_in[0];
    const float* qpos  = (const float*)d_in[1];
    const float* value = (const float*)d_in[2];
    const float* ref   = (const float*)d_in[3];
    const int*   ss    = (const int*)d_in[4];
    const float* sa_off_w = (const float*)d_in[5];
    const float* sa_off_b = (const float*)d_in[6];
    const float* sa_aw_w  = (const float*)d_in[7];
    const float* sa_aw_b  = (const float*)d_in[8];
    const float* sa_vp_w  = (const float*)d_in[9];
    const float* sa_vp_b  = (const float*)d_in[10];
    const float* sa_op_w  = (const float*)d_in[11];
    const float* sa_op_b  = (const float*)d_in[12];
    const float* ca_off_w = (const float*)d_in[13];
    const float* ca_off_b = (const float*)d_in[14];
    const float* ca_aw_w  = (const float*)d_in[15];
    const float* ca_aw_b  = (const float*)d_in[16];
    const float* ca_vp_w  = (const float*)d_in[17];
    const float* ca_vp_b  = (const float*)d_in[18];
    const float* ca_op_w  = (const float*)d_in[19];
    const float* ca_op_b  = (const float*)d_in[20];
    const float* ffn_w1   = (const float*)d_in[21];
    const float* ffn_b1   = (const float*)d_in[22];
    const float* ffn_w2   = (const float*)d_in[23];
    const float* ffn_b2   = (const float*)d_in[24];
    const float* ln1_g = (const float*)d_in[25];
    const float* ln1_b = (const float*)d_in[26];
    const float* ln2_g = (const float*)d_in[27];
    const float* ln2_b = (const float*)d_in[28];
    const float* ln3_g = (const float*)d_in[29];
    const float* ln3_b = (const float*)d_in[30];

    // ---- final output layout (fp32) ----
    float* outf    = (float*)d_out;
    float* out_q   = outf;                            // [Q,C]
    float* out_qp  = outf + QC;                       // [Q,C]
    float* out_val = outf + 2 * (size_t)QC;           // [2Q,C]
    float* out_ref = outf + 4 * (size_t)QC;           // [Q,LC,2]
    float* out_ss  = outf + 4 * (size_t)QC + REFN;    // [4]

    // ---- d_out doubles as bf16 body scratch (all dead before final writes) ----
    ushort_t* dsc    = (ushort_t*)d_out;
    ushort_t* vbuf   = dsc;                           // 2QC bf16 (head-major value)
    ushort_t* tmp    = dsc + 2 * (size_t)QC;          // QC bf16
    ushort_t* offb   = dsc + 3 * (size_t)QC;          // Q*128
    ushort_t* awb    = dsc + 3 * (size_t)QC + (size_t)Q_ * 128;  // Q*64
    ushort_t* hidden = dsc;                           // Q*1024 bf16

    // ---- workspace: ~42.8 MB bf16 ----
    char* base = (char*)d_ws;
    size_t offbyte = 0;
    auto alloc = [&](size_t elems) -> ushort_t* {
        ushort_t* p = (ushort_t*)(base + offbyte);
        offbyte += ((elems * 2 + 255) / 256) * 256;
        return p;
    };
    ushort_t* wt_sa_off = alloc(256 * 64);
    ushort_t* wt_sa_aw  = alloc(256 * 32);
    ushort_t* wt_sa_vp  = alloc(256 * 256);
    ushort_t* wt_sa_op  = alloc(256 * 256);
    ushort_t* wt_ca_off = alloc(256 * 128);
    ushort_t* wt_ca_aw  = alloc(256 * 64);
    ushort_t* wt_ca_vp  = alloc(256 * 256);
    ushort_t* wt_ca_op  = alloc(256 * 256);
    ushort_t* wt_ffn1   = alloc(256 * 1024);
    ushort_t* wt_ffn2   = alloc(1024 * 256);
    ushort_t* qpq  = alloc(QC);     // bf16(q+pos), then bf16(q1+pos)
    ushort_t* attn = alloc(QC);     // sampled attention out; later q2 (LN2 out)
    ushort_t* q1   = alloc(QC);     // LN1 out; later FFN2 out
    ushort_t* q2   = attn;          // LN2 out overlays dead attn

    TAll td;
    const float* srcs[10] = {sa_off_w, sa_aw_w, sa_vp_w, sa_op_w, ca_off_w,
                             ca_aw_w, ca_vp_w, ca_op_w, ffn_w1, ffn_w2};
    ushort_t* dsts[10] = {wt_sa_off, wt_sa_aw, wt_sa_vp, wt_sa_op, wt_ca_off,
                          wt_ca_aw, wt_ca_vp, wt_ca_op, wt_ffn1, wt_ffn2};
    int Ks[10] = {256, 256, 256, 256, 256, 256, 256, 256, 256, 1024};
    int Ns[10] = {64, 32, 256, 256, 128, 64, 256, 256, 1024, 256};
    for (int m = 0; m < 10; m++) { td.t[m] = {srcs[m], dsts[m], Ks[m], Ns[m]}; }

    // 1. prologue
    prologue_kernel<<<(PRO_TOTAL + 255) / 256, 256, 0, stream>>>(query, qpos, qpq, td);

    // ---- self-attention (L=1, value = raw fp32 query) ----
    gemm_bf16<4, false, 0, true, true><<<dim3(Q_ / 128, 4), 256, 0, stream>>>(
        nullptr, query, wt_sa_vp, sa_vp_b, nullptr, nullptr, vbuf, Q_, 256, 256);
    gemm_bf16<4, false, 0, false, false><<<dim3(Q_ / 128, 1), 256, 0, stream>>>(
        qpq, nullptr, wt_sa_off, sa_off_b, nullptr, nullptr, offb, Q_, 64, 256);
    gemm_bf16<2, false, 0, false, false><<<dim3(Q_ / 128, 1), 256, 0, stream>>>(
        qpq, nullptr, wt_sa_aw, sa_aw_b, nullptr, nullptr, awb, Q_, 32, 256);
    sample_kernel<1><<<(Q_ * NH_) / 32, 256, 0, stream>>>(vbuf, offb, awb, ref, attn);
    gemm_bf16<4, false, 2, false, false><<<dim3(Q_ / 128, 4), 256, 0, stream>>>(
        attn, nullptr, wt_sa_op, sa_op_b, nullptr, query, tmp, Q_, 256, 256);
    ln_kernel<false><<<Q_ / 4, 256, 0, stream>>>(tmp, ln1_g, ln1_b, q1, nullptr, qpos, qpq);

    // ---- cross-attention (L=2, value = raw fp32 value) ----
    gemm_bf16<4, false, 0, true, true><<<dim3(2 * Q_ / 128, 4), 256, 0, stream>>>(
        nullptr, value, wt_ca_vp, ca_vp_b, nullptr, nullptr, vbuf, 2 * Q_, 256, 256);
    gemm_bf16<4, false, 0, false, false><<<dim3(Q_ / 128, 2), 256, 0, stream>>>(
        qpq, nullptr, wt_ca_off, ca_off_b, nullptr, nullptr, offb, Q_, 128, 256);
    gemm_bf16<4, false, 0, false, false><<<dim3(Q_ / 128, 1), 256, 0, stream>>>(
        qpq, nullptr, wt_ca_aw, ca_aw_b, nullptr, nullptr, awb, Q_, 64, 256);
    sample_kernel<2><<<(Q_ * NH_) / 32, 256, 0, stream>>>(vbuf, offb, awb, ref, attn);
    gemm_bf16<4, false, 1, false, false><<<dim3(Q_ / 128, 4), 256, 0, stream>>>(
        attn, nullptr, wt_ca_op, ca_op_b, q1, nullptr, tmp, Q_, 256, 256);
    ln_kernel<false><<<Q_ / 4, 256, 0, stream>>>(tmp, ln2_g, ln2_b, q2, nullptr, nullptr, nullptr);

    // ---- FFN ----
    gemm_bf16<4, true, 0, false, false><<<dim3(Q_ / 128, 16), 256, 0, stream>>>(
        q2, nullptr, wt_ffn1, ffn_b1, nullptr, nullptr, hidden, Q_, 1024, 256);
    gemm_bf16<4, false, 1, false, false><<<dim3(Q_ / 128, 4), 256, 0, stream>>>(
        hidden, nullptr, wt_ffn2, ffn_b2, q2, nullptr, q1, Q_, 256, 1024);
    // LN3 -> fp32 final output (overlays dead hidden region)
    ln_kernel<true><<<Q_ / 4, 256, 0, stream>>>(q1, ln3_g, ln3_b, nullptr, out_q, nullptr, nullptr);

    // ---- passthrough outputs: pure fp32 D2D copies (scratch regions now dead) ----
    hipMemcpyAsync(out_qp,  qpos,  (size_t)QC * 4,  hipMemcpyDeviceToDevice, stream);
    hipMemcpyAsync(out_val, value, (size_t)VC * 4,  hipMemcpyDeviceToDevice, stream);
    hipMemcpyAsync(out_ref, ref,   (size_t)REFN * 4, hipMemcpyDeviceToDevice, stream);
    ss_kernel<<<1, 64, 0, stream>>>(ss, out_ss);

    (void)in_sizes; (void)n_in; (void)out_size; (void)ws_size;
}

// Round 7
// 617.224 us; speedup vs baseline: 1.1078x; 1.1078x over previous
//
#include <hip/hip_runtime.h>

// ---------------- problem constants ----------------
#define Q_   25600
#define C_   256
#define NH_  8
#define HD_  32
#define NP_  4
#define LC_  2
#define HW_  160          // H == W == 160

#define QC   (Q_ * C_)            // 6,553,600
#define VC   (2 * QC)             // 13,107,200
#define REFN (Q_ * LC_ * 2)       // 102,400

typedef unsigned short ushort_t;
typedef __attribute__((ext_vector_type(8))) short short8;
typedef __attribute__((ext_vector_type(4))) float f32x4;

// ---------------- bf16 helpers ----------------
__device__ __forceinline__ float b2f(ushort_t u) {
    union { unsigned int u32; float f; } c; c.u32 = ((unsigned int)u) << 16; return c.f;
}
__device__ __forceinline__ ushort_t f2b(float f) {
    union { float f; unsigned int u32; } c; c.f = f;
    unsigned int u = c.u32;
    return (ushort_t)((u + 0x7FFFu + ((u >> 16) & 1u)) >> 16);
}
__device__ __forceinline__ unsigned int pack2(float lo, float hi){
    return (unsigned int)f2b(lo) | ((unsigned int)f2b(hi) << 16);
}
__device__ __forceinline__ short8 pack8(float4 a, float4 b){
    union { short8 s; ushort_t u[8]; } r;
    r.u[0]=f2b(a.x); r.u[1]=f2b(a.y); r.u[2]=f2b(a.z); r.u[3]=f2b(a.w);
    r.u[4]=f2b(b.x); r.u[5]=f2b(b.y); r.u[6]=f2b(b.z); r.u[7]=f2b(b.w);
    return r.s;
}
__device__ __forceinline__ float uasf(unsigned int u){
    union { unsigned int u32; float f; } c; c.u32 = u; return c.f;
}
// unpack 4 bf16 (packed in uint2) -> 4 floats
__device__ __forceinline__ float4 unpk4(uint2 u){
    float4 r;
    r.x = uasf(u.x << 16); r.y = uasf(u.x & 0xFFFF0000u);
    r.z = uasf(u.y << 16); r.w = uasf(u.y & 0xFFFF0000u);
    return r;
}

// ---------------- prologue: qpq = bf16(query+qpos) + weight transposes (fp32->bf16) ----------------
struct TDesc { const float* src; ushort_t* dst; int K; int N; };
struct TAll  { TDesc t[10]; };

#define QC4   (QC / 4)        // 1,638,400
#define TRANS_TOTAL 860160
#define PRO_TOTAL (QC4 + TRANS_TOTAL)

__global__ __launch_bounds__(256) void prologue_kernel(
    const float* __restrict__ query, const float* __restrict__ qpos,
    ushort_t* __restrict__ qpq, TAll td)
{
    int i = blockIdx.x * 256 + threadIdx.x;
    if (i < QC4) {
        float4 qv = ((const float4*)query)[i];
        float4 pv = ((const float4*)qpos)[i];
        uint2 o;
        o.x = pack2(qv.x + pv.x, qv.y + pv.y);
        o.y = pack2(qv.z + pv.z, qv.w + pv.w);
        ((uint2*)qpq)[i] = o;
        return;
    }
    i -= QC4;
    #pragma unroll 1
    for (int m = 0; m < 10; m++) {
        int sz = td.t[m].K * td.t[m].N;
        if (i < sz) {
            int N = td.t[m].N, K = td.t[m].K;
            int k = i / N, n = i - k * N;
            td.t[m].dst[(size_t)n * K + k] = f2b(td.t[m].src[i]);
            return;
        }
        i -= sz;
    }
}

// ---------------- tiny: spatial_shapes int32 -> fp32 ----------------
__global__ void ss_kernel(const int* __restrict__ ss, float* __restrict__ out_ss)
{
    int i = threadIdx.x;
    if (i < 4) out_ss[i] = (float)ss[i];
}

// ---------------- MFMA GEMM ----------------
// C = A[M,K] @ B[K,N] + bias (+res) (+relu).  Bt = B^T [N,K] bf16.
// Per-wave tile 64x(16*WN); block = 4 waves stacked in M -> 256 rows/block.
// bf16-A path: k-loop unrolled x2 (16 loads in flight per stall, 32 MFMAs
// per stall) -- halves the number of latency stalls per wave. AF32 path
// keeps step-32 (fp32 fragments are 2x the registers).
// RESM: 0 none, 1 bf16 residual, 2 fp32 residual.
// VOUT: write head-major value layout [(col>>5)*M + row][32] instead of [row][N].
template<int WN, bool RELU, int RESM, bool AF32, bool VOUT>
__global__ __launch_bounds__(256) void gemm_bf16(
    const ushort_t* __restrict__ A16, const float* __restrict__ A32,
    const ushort_t* __restrict__ Bt, const float* __restrict__ bias,
    const ushort_t* __restrict__ res16, const float* __restrict__ res32,
    ushort_t* __restrict__ Cout, int M, int N, int K)
{
    const int lane = threadIdx.x & 63;
    const int wave = threadIdx.x >> 6;
    const int m0 = blockIdx.x * 256 + wave * 64;
    const int n0 = blockIdx.y * (16 * WN);
    const int r = lane & 15, quad = lane >> 4;

    f32x4 acc[4][WN];
    #pragma unroll
    for (int i = 0; i < 4; i++)
        #pragma unroll
        for (int j = 0; j < WN; j++) acc[i][j] = (f32x4){0.f, 0.f, 0.f, 0.f};

    const ushort_t* Ab16 = AF32 ? nullptr : (A16 + (size_t)(m0 + r) * K + quad * 8);
    const float*    Ab32 = AF32 ? (A32 + (size_t)(m0 + r) * K + quad * 8) : nullptr;
    const ushort_t* Bbase = Bt + (size_t)(n0 + r) * K + quad * 8;

    if (AF32) {
        for (int k0 = 0; k0 < K; k0 += 32) {
            short8 af[4], bfr[WN];
            #pragma unroll
            for (int i = 0; i < 4; i++) {
                float4 u = *(const float4*)(Ab32 + (size_t)i * 16 * K + k0);
                float4 v = *(const float4*)(Ab32 + (size_t)i * 16 * K + k0 + 4);
                af[i] = pack8(u, v);
            }
            #pragma unroll
            for (int j = 0; j < WN; j++)
                bfr[j] = *(const short8*)(Bbase + (size_t)j * 16 * K + k0);
            #pragma unroll
            for (int i = 0; i < 4; i++)
                #pragma unroll
                for (int j = 0; j < WN; j++)
                    acc[i][j] = __builtin_amdgcn_mfma_f32_16x16x32_bf16(af[i], bfr[j], acc[i][j], 0, 0, 0);
        }
    } else {
        // K is a multiple of 64 for all bf16-A GEMMs (256 or 1024)
        for (int k0 = 0; k0 < K; k0 += 64) {
            short8 af0[4], af1[4], b0[WN], b1[WN];
            #pragma unroll
            for (int i = 0; i < 4; i++) {
                af0[i] = *(const short8*)(Ab16 + (size_t)i * 16 * K + k0);
                af1[i] = *(const short8*)(Ab16 + (size_t)i * 16 * K + k0 + 32);
            }
            #pragma unroll
            for (int j = 0; j < WN; j++) {
                b0[j] = *(const short8*)(Bbase + (size_t)j * 16 * K + k0);
                b1[j] = *(const short8*)(Bbase + (size_t)j * 16 * K + k0 + 32);
            }
            #pragma unroll
            for (int i = 0; i < 4; i++)
                #pragma unroll
                for (int j = 0; j < WN; j++)
                    acc[i][j] = __builtin_amdgcn_mfma_f32_16x16x32_bf16(af0[i], b0[j], acc[i][j], 0, 0, 0);
            #pragma unroll
            for (int i = 0; i < 4; i++)
                #pragma unroll
                for (int j = 0; j < WN; j++)
                    acc[i][j] = __builtin_amdgcn_mfma_f32_16x16x32_bf16(af1[i], b1[j], acc[i][j], 0, 0, 0);
        }
    }

    float bv[WN];
    #pragma unroll
    for (int j = 0; j < WN; j++) bv[j] = bias[n0 + j * 16 + r];

    #pragma unroll
    for (int i = 0; i < 4; i++) {
        int row = m0 + i * 16 + quad * 4;
        #pragma unroll
        for (int j = 0; j < WN; j++) {
            int col = n0 + j * 16 + r;
            #pragma unroll
            for (int t = 0; t < 4; t++) {
                float v = acc[i][j][t] + bv[j];
                if (RESM == 1) v += b2f(res16[(size_t)(row + t) * N + col]);
                if (RESM == 2) v += res32[(size_t)(row + t) * N + col];
                if (RELU) v = fmaxf(v, 0.f);
                if (VOUT) {
                    // head-major: [(head)*M + row][32]; head = col>>5, ch = col&31
                    Cout[((size_t)(col >> 5) * (size_t)M + (size_t)(row + t)) * HD_ + (col & 31)] = f2b(v);
                } else {
                    Cout[(size_t)(row + t) * N + col] = f2b(v);
                }
            }
        }
    }
}

// ---------------- fused softmax + bilinear sampling ----------------
// v layout: [(h*L + l)*Q + pix][HD]  (head-major, 64 B per pixel record)
// 8 lanes per (q,h) group; each lane owns 4 channels (uint2 corner loads).
template<int L>
__global__ __launch_bounds__(256) void sample_kernel(
    const ushort_t* __restrict__ v,    // head-major projected value (bf16)
    const ushort_t* __restrict__ off,  // [Q, NH*L*NP*2] (bf16)
    const ushort_t* __restrict__ aw,   // [Q, NH*L*NP] raw logits (bf16)
    const float*    __restrict__ ref,  // [Q, LC, 2] fp32
    ushort_t* __restrict__ outp)       // [Q, C] bf16
{
    const int t   = blockIdx.x * 256 + threadIdx.x;
    const int g   = t >> 3;            // (q,h) group
    const int sub = t & 7;             // 4-channel slice within head
    const int q   = g >> 3;
    const int h   = g & 7;
    const int P   = L * NP_;

    // ---- softmax over P logits (vectorized bf16 load, normalized in-place) ----
    float w[2 * NP_];
    {
        union { uint4 q4; uint2 q2; ushort_t u[8]; } ab;
        const ushort_t* awp = aw + (size_t)q * (NH_ * P) + h * P;
        if (L == 2) ab.q4 = *(const uint4*)awp;
        else        ab.q2 = *(const uint2*)awp;
        float mx = -1e30f;
        #pragma unroll
        for (int i = 0; i < P; i++) { w[i] = b2f(ab.u[i]); mx = fmaxf(mx, w[i]); }
        float s = 0.f;
        #pragma unroll
        for (int i = 0; i < P; i++) { w[i] = __expf(w[i] - mx); s += w[i]; }
        float inv = 1.f / s;
        #pragma unroll
        for (int i = 0; i < P; i++) w[i] *= inv;
    }

    // ---- offsets (vectorized bf16 load) ----
    float offx[2 * NP_], offy[2 * NP_];
    {
        union { uint4 q4[2]; ushort_t u[16]; } ob;
        const ushort_t* offp = off + (size_t)q * (NH_ * P * 2) + h * (P * 2);
        ob.q4[0] = *(const uint4*)offp;
        if (L == 2) ob.q4[1] = *(const uint4*)(offp + 8);
        #pragma unroll
        for (int i = 0; i < P; i++) { offx[i] = b2f(ob.u[2 * i]); offy[i] = b2f(ob.u[2 * i + 1]); }
    }

    const ushort_t* vh = v + ((size_t)(h * L) * Q_) * HD_ + sub * 4;
    float4 acc = {0.f, 0.f, 0.f, 0.f};

    #pragma unroll
    for (int l = 0; l < L; l++) {
        float rx = ref[((size_t)q * LC_ + l) * 2 + 0] * (float)HW_ - 0.5f;
        float ry = ref[((size_t)q * LC_ + l) * 2 + 1] * (float)HW_ - 0.5f;
        const ushort_t* vl = vh + (size_t)l * ((size_t)Q_ * HD_);
        #pragma unroll
        for (int p = 0; p < NP_; p++) {
            const int ip = l * NP_ + p;
            float x = rx + offx[ip];
            float y = ry + offy[ip];
            x = fminf(fmaxf(x, -1e4f), 1e4f);
            y = fminf(fmaxf(y, -1e4f), 1e4f);
            float xf = floorf(x), yf = floorf(y);
            float tx = x - xf, ty = y - yf;
            int x0 = (int)xf, y0 = (int)yf;
            int x1 = x0 + 1, y1 = y0 + 1;
            int xc0 = min(max(x0, 0), HW_ - 1), xc1 = min(max(x1, 0), HW_ - 1);
            int yc0 = min(max(y0, 0), HW_ - 1), yc1 = min(max(y1, 0), HW_ - 1);
            bool vx0 = (unsigned)x0 < (unsigned)HW_, vx1 = (unsigned)x1 < (unsigned)HW_;
            bool vy0 = (unsigned)y0 < (unsigned)HW_, vy1 = (unsigned)y1 < (unsigned)HW_;

            // fold attention weight + validity into the 4 corner weights
            float aww = w[ip];
            float w00 = (1.f - tx) * (1.f - ty) * aww;
            float w10 = tx * (1.f - ty) * aww;
            float w01 = (1.f - tx) * ty * aww;
            float w11 = tx * ty * aww;
            w00 = (vx0 & vy0) ? w00 : 0.f;
            w10 = (vx1 & vy0) ? w10 : 0.f;
            w01 = (vx0 & vy1) ? w01 : 0.f;
            w11 = (vx1 & vy1) ? w11 : 0.f;

            int r0 = yc0 * HW_, r1 = yc1 * HW_;
            uint2 u00 = *(const uint2*)(vl + (size_t)(r0 + xc0) * HD_);
            uint2 u10 = *(const uint2*)(vl + (size_t)(r0 + xc1) * HD_);
            uint2 u01 = *(const uint2*)(vl + (size_t)(r1 + xc0) * HD_);
            uint2 u11 = *(const uint2*)(vl + (size_t)(r1 + xc1) * HD_);
            float4 c00 = unpk4(u00), c10 = unpk4(u10), c01 = unpk4(u01), c11 = unpk4(u11);

            acc.x += c00.x * w00 + c10.x * w10 + c01.x * w01 + c11.x * w11;
            acc.y += c00.y * w00 + c10.y * w10 + c01.y * w01 + c11.y * w11;
            acc.z += c00.z * w00 + c10.z * w10 + c01.z * w01 + c11.z * w11;
            acc.w += c00.w * w00 + c10.w * w10 + c01.w * w01 + c11.w * w11;
        }
    }

    uint2 o;
    o.x = pack2(acc.x, acc.y);
    o.y = pack2(acc.z, acc.w);
    *(uint2*)(outp + (size_t)q * C_ + h * HD_ + sub * 4) = o;
}

// ---------------- LayerNorm (wave per row of 256) ----------------
// x bf16; gamma/beta fp32. OUT32: y32 fp32 out, else y16 bf16 out.
// optional y2 (bf16) = y + qpos (qpos fp32).
template<bool OUT32>
__global__ __launch_bounds__(256) void ln_kernel(
    const ushort_t* __restrict__ x, const float* __restrict__ g,
    const float* __restrict__ b, ushort_t* __restrict__ y16,
    float* __restrict__ y32,
    const float* __restrict__ qpos, ushort_t* __restrict__ y2)
{
    const int lane = threadIdx.x & 63;
    const int wave = threadIdx.x >> 6;
    const size_t row = (size_t)blockIdx.x * 4 + wave;
    const size_t base = row * C_ + lane * 4;

    uint2 xv = *(const uint2*)(x + base);
    float f0 = b2f((ushort_t)(xv.x & 0xFFFF)), f1 = b2f((ushort_t)(xv.x >> 16));
    float f2 = b2f((ushort_t)(xv.y & 0xFFFF)), f3 = b2f((ushort_t)(xv.y >> 16));
    float s  = f0 + f1 + f2 + f3;
    float sq = f0 * f0 + f1 * f1 + f2 * f2 + f3 * f3;
    #pragma unroll
    for (int m = 1; m < 64; m <<= 1) { s += __shfl_xor(s, m, 64); sq += __shfl_xor(sq, m, 64); }
    float mean = s * (1.f / 256.f);
    float var  = sq * (1.f / 256.f) - mean * mean;
    float rinv = rsqrtf(fmaxf(var, 0.f) + 1e-5f);

    float4 gv = *(const float4*)(g + lane * 4);
    float4 bv = *(const float4*)(b + lane * 4);
    float o0 = (f0 - mean) * rinv * gv.x + bv.x;
    float o1 = (f1 - mean) * rinv * gv.y + bv.y;
    float o2 = (f2 - mean) * rinv * gv.z + bv.z;
    float o3 = (f3 - mean) * rinv * gv.w + bv.w;

    if (OUT32) {
        float4 o; o.x = o0; o.y = o1; o.z = o2; o.w = o3;
        *(float4*)(y32 + base) = o;
    } else {
        uint2 ov; ov.x = pack2(o0, o1); ov.y = pack2(o2, o3);
        *(uint2*)(y16 + base) = ov;
    }

    if (y2) {
        float4 pv = *(const float4*)(qpos + base);
        uint2 o2v;
        o2v.x = pack2(o0 + pv.x, o1 + pv.y);
        o2v.y = pack2(o2 + pv.z, o3 + pv.w);
        *(uint2*)(y2 + base) = o2v;
    }
}

// ---------------- host ----------------
extern "C" void kernel_launch(void* const* d_in, const int* in_sizes, int n_in,
                              void* d_out, int out_size, void* d_ws, size_t ws_size,
                              hipStream_t stream)
{
    const float* query = (const float*)d_in[0];
    const float* qpos  = (const float*)d_in[1];
    const float* value = (const float*)d_in[2];
    const float* ref   = (const float*)d_in[3];
    const int*   ss    = (const int*)d_in[4];
    const float* sa_off_w = (const float*)d_in[5];
    const float* sa_off_b = (const float*)d_in[6];
    const float* sa_aw_w  = (const float*)d_in[7];
    const float* sa_aw_b  = (const float*)d_in[8];
    const float* sa_vp_w  = (const float*)d_in[9];
    const float* sa_vp_b  = (const float*)d_in[10];
    const float* sa_op_w  = (const float*)d_in[11];
    const float* sa_op_b  = (const float*)d_in[12];
    const float* ca_off_w = (const float*)d_in[13];
    const float* ca_off_b = (const float*)d_in[14];
    const float* ca_aw_w  = (const float*)d_in[15];
    const float* ca_aw_b  = (const float*)d_in[16];
    const float* ca_vp_w  = (const float*)d_in[17];
    const float* ca_vp_b  = (const float*)d_in[18];
    const float* ca_op_w  = (const float*)d_in[19];
    const float* ca_op_b  = (const float*)d_in[20];
    const float* ffn_w1   = (const float*)d_in[21];
    const float* ffn_b1   = (const float*)d_in[22];
    const float* ffn_w2   = (const float*)d_in[23];
    const float* ffn_b2   = (const float*)d_in[24];
    const float* ln1_g = (const float*)d_in[25];
    const float* ln1_b = (const float*)d_in[26];
    const float* ln2_g = (const float*)d_in[27];
    const float* ln2_b = (const float*)d_in[28];
    const float* ln3_g = (const float*)d_in[29];
    const float* ln3_b = (const float*)d_in[30];

    // ---- final output layout (fp32) ----
    float* outf    = (float*)d_out;
    float* out_q   = outf;                            // [Q,C]
    float* out_qp  = outf + QC;                       // [Q,C]
    float* out_val = outf + 2 * (size_t)QC;           // [2Q,C]
    float* out_ref = outf + 4 * (size_t)QC;           // [Q,LC,2]
    float* out_ss  = outf + 4 * (size_t)QC + REFN;    // [4]

    // ---- d_out doubles as bf16 body scratch (all dead before final writes) ----
    ushort_t* dsc    = (ushort_t*)d_out;
    ushort_t* vbuf   = dsc;                           // 2QC bf16 (head-major value)
    ushort_t* tmp    = dsc + 2 * (size_t)QC;          // QC bf16
    ushort_t* offb   = dsc + 3 * (size_t)QC;          // Q*128
    ushort_t* awb    = dsc + 3 * (size_t)QC + (size_t)Q_ * 128;  // Q*64
    ushort_t* hidden = dsc;                           // Q*1024 bf16

    // ---- workspace: ~42.8 MB bf16 ----
    char* base = (char*)d_ws;
    size_t offbyte = 0;
    auto alloc = [&](size_t elems) -> ushort_t* {
        ushort_t* p = (ushort_t*)(base + offbyte);
        offbyte += ((elems * 2 + 255) / 256) * 256;
        return p;
    };
    ushort_t* wt_sa_off = alloc(256 * 64);
    ushort_t* wt_sa_aw  = alloc(256 * 32);
    ushort_t* wt_sa_vp  = alloc(256 * 256);
    ushort_t* wt_sa_op  = alloc(256 * 256);
    ushort_t* wt_ca_off = alloc(256 * 128);
    ushort_t* wt_ca_aw  = alloc(256 * 64);
    ushort_t* wt_ca_vp  = alloc(256 * 256);
    ushort_t* wt_ca_op  = alloc(256 * 256);
    ushort_t* wt_ffn1   = alloc(256 * 1024);
    ushort_t* wt_ffn2   = alloc(1024 * 256);
    ushort_t* qpq  = alloc(QC);     // bf16(q+pos), then bf16(q1+pos)
    ushort_t* attn = alloc(QC);     // sampled attention out; later q2 (LN2 out)
    ushort_t* q1   = alloc(QC);     // LN1 out; later FFN2 out
    ushort_t* q2   = attn;          // LN2 out overlays dead attn

    TAll td;
    const float* srcs[10] = {sa_off_w, sa_aw_w, sa_vp_w, sa_op_w, ca_off_w,
                             ca_aw_w, ca_vp_w, ca_op_w, ffn_w1, ffn_w2};
    ushort_t* dsts[10] = {wt_sa_off, wt_sa_aw, wt_sa_vp, wt_sa_op, wt_ca_off,
                          wt_ca_aw, wt_ca_vp, wt_ca_op, wt_ffn1, wt_ffn2};
    int Ks[10] = {256, 256, 256, 256, 256, 256, 256, 256, 256, 1024};
    int Ns[10] = {64, 32, 256, 256, 128, 64, 256, 256, 1024, 256};
    for (int m = 0; m < 10; m++) { td.t[m] = {srcs[m], dsts[m], Ks[m], Ns[m]}; }

    // 1. prologue
    prologue_kernel<<<(PRO_TOTAL + 255) / 256, 256, 0, stream>>>(query, qpos, qpq, td);

    // ---- self-attention (L=1, value = raw fp32 query) ----
    gemm_bf16<4, false, 0, true, true><<<dim3(Q_ / 256, 4), 256, 0, stream>>>(
        nullptr, query, wt_sa_vp, sa_vp_b, nullptr, nullptr, vbuf, Q_, 256, 256);
    gemm_bf16<4, false, 0, false, false><<<dim3(Q_ / 256, 1), 256, 0, stream>>>(
        qpq, nullptr, wt_sa_off, sa_off_b, nullptr, nullptr, offb, Q_, 64, 256);
    gemm_bf16<2, false, 0, false, false><<<dim3(Q_ / 256, 1), 256, 0, stream>>>(
        qpq, nullptr, wt_sa_aw, sa_aw_b, nullptr, nullptr, awb, Q_, 32, 256);
    sample_kernel<1><<<(Q_ * NH_) / 32, 256, 0, stream>>>(vbuf, offb, awb, ref, attn);
    gemm_bf16<4, false, 2, false, false><<<dim3(Q_ / 256, 4), 256, 0, stream>>>(
        attn, nullptr, wt_sa_op, sa_op_b, nullptr, query, tmp, Q_, 256, 256);
    ln_kernel<false><<<Q_ / 4, 256, 0, stream>>>(tmp, ln1_g, ln1_b, q1, nullptr, qpos, qpq);

    // ---- cross-attention (L=2, value = raw fp32 value) ----
    gemm_bf16<4, false, 0, true, true><<<dim3(2 * Q_ / 256, 4), 256, 0, stream>>>(
        nullptr, value, wt_ca_vp, ca_vp_b, nullptr, nullptr, vbuf, 2 * Q_, 256, 256);
    gemm_bf16<4, false, 0, false, false><<<dim3(Q_ / 256, 2), 256, 0, stream>>>(
        qpq, nullptr, wt_ca_off, ca_off_b, nullptr, nullptr, offb, Q_, 128, 256);
    gemm_bf16<4, false, 0, false, false><<<dim3(Q_ / 256, 1), 256, 0, stream>>>(
        qpq, nullptr, wt_ca_aw, ca_aw_b, nullptr, nullptr, awb, Q_, 64, 256);
    sample_kernel<2><<<(Q_ * NH_) / 32, 256, 0, stream>>>(vbuf, offb, awb, ref, attn);
    gemm_bf16<4, false, 1, false, false><<<dim3(Q_ / 256, 4), 256, 0, stream>>>(
        attn, nullptr, wt_ca_op, ca_op_b, q1, nullptr, tmp, Q_, 256, 256);
    ln_kernel<false><<<Q_ / 4, 256, 0, stream>>>(tmp, ln2_g, ln2_b, q2, nullptr, nullptr, nullptr);

    // ---- FFN ----
    gemm_bf16<4, true, 0, false, false><<<dim3(Q_ / 256, 16), 256, 0, stream>>>(
        q2, nullptr, wt_ffn1, ffn_b1, nullptr, nullptr, hidden, Q_, 1024, 256);
    gemm_bf16<4, false, 1, false, false><<<dim3(Q_ / 256, 4), 256, 0, stream>>>(
        hidden, nullptr, wt_ffn2, ffn_b2, q2, nullptr, q1, Q_, 256, 1024);
    // LN3 -> fp32 final output (overlays dead hidden region)
    ln_kernel<true><<<Q_ / 4, 256, 0, stream>>>(q1, ln3_g, ln3_b, nullptr, out_q, nullptr, nullptr);

    // ---- passthrough outputs: pure fp32 D2D copies (scratch regions now dead) ----
    hipMemcpyAsync(out_qp,  qpos,  (size_t)QC * 4,  hipMemcpyDeviceToDevice, stream);
    hipMemcpyAsync(out_val, value, (size_t)VC * 4,  hipMemcpyDeviceToDevice, stream);
    hipMemcpyAsync(out_ref, ref,   (size_t)REFN * 4, hipMemcpyDeviceToDevice, stream);
    ss_kernel<<<1, 64, 0, stream>>>(ss, out_ss);

    (void)in_sizes; (void)n_in; (void)out_size; (void)ws_size;
}

// Round 8
// 509.319 us; speedup vs baseline: 1.3425x; 1.2119x over previous
//
#include <hip/hip_runtime.h>

// ---------------- problem constants ----------------
#define Q_   25600
#define C_   256
#define NH_  8
#define HD_  32
#define NP_  4
#define LC_  2
#define HW_  160          // H == W == 160

#define QC   (Q_ * C_)            // 6,553,600
#define VC   (2 * QC)             // 13,107,200
#define REFN (Q_ * LC_ * 2)       // 102,400

typedef unsigned short ushort_t;
typedef __attribute__((ext_vector_type(8))) short short8;
typedef __attribute__((ext_vector_type(4))) float f32x4;

// ---------------- bf16 helpers ----------------
__device__ __forceinline__ float b2f(ushort_t u) {
    union { unsigned int u32; float f; } c; c.u32 = ((unsigned int)u) << 16; return c.f;
}
__device__ __forceinline__ ushort_t f2b(float f) {
    union { float f; unsigned int u32; } c; c.f = f;
    unsigned int u = c.u32;
    return (ushort_t)((u + 0x7FFFu + ((u >> 16) & 1u)) >> 16);
}
__device__ __forceinline__ unsigned int pack2(float lo, float hi){
    return (unsigned int)f2b(lo) | ((unsigned int)f2b(hi) << 16);
}
__device__ __forceinline__ short8 pack8(float4 a, float4 b){
    union { short8 s; ushort_t u[8]; } r;
    r.u[0]=f2b(a.x); r.u[1]=f2b(a.y); r.u[2]=f2b(a.z); r.u[3]=f2b(a.w);
    r.u[4]=f2b(b.x); r.u[5]=f2b(b.y); r.u[6]=f2b(b.z); r.u[7]=f2b(b.w);
    return r.s;
}
__device__ __forceinline__ float uasf(unsigned int u){
    union { unsigned int u32; float f; } c; c.u32 = u; return c.f;
}
// unpack 4 bf16 (packed in uint2) -> 4 floats
__device__ __forceinline__ float4 unpk4(uint2 u){
    float4 r;
    r.x = uasf(u.x << 16); r.y = uasf(u.x & 0xFFFF0000u);
    r.z = uasf(u.y << 16); r.w = uasf(u.y & 0xFFFF0000u);
    return r;
}

// async global->LDS, 16 B per lane; LDS dest = wave-uniform base + lane*16
__device__ __forceinline__ void gload16(const void* g, void* l) {
    __builtin_amdgcn_global_load_lds(
        (const __attribute__((address_space(1))) void*)(uintptr_t)(g),
        (__attribute__((address_space(3))) void*)(uintptr_t)(l), 16, 0, 0);
}

// ---------------- prologue: qpq = bf16(query+qpos) + weight transposes (fp32->bf16) ----------------
struct TDesc { const float* src; ushort_t* dst; int K; int N; };
struct TAll  { TDesc t[10]; };

#define QC4   (QC / 4)        // 1,638,400
#define TRANS_TOTAL 860160
#define PRO_TOTAL (QC4 + TRANS_TOTAL)

__global__ __launch_bounds__(256) void prologue_kernel(
    const float* __restrict__ query, const float* __restrict__ qpos,
    ushort_t* __restrict__ qpq, TAll td)
{
    int i = blockIdx.x * 256 + threadIdx.x;
    if (i < QC4) {
        float4 qv = ((const float4*)query)[i];
        float4 pv = ((const float4*)qpos)[i];
        uint2 o;
        o.x = pack2(qv.x + pv.x, qv.y + pv.y);
        o.y = pack2(qv.z + pv.z, qv.w + pv.w);
        ((uint2*)qpq)[i] = o;
        return;
    }
    i -= QC4;
    #pragma unroll 1
    for (int m = 0; m < 10; m++) {
        int sz = td.t[m].K * td.t[m].N;
        if (i < sz) {
            int N = td.t[m].N, K = td.t[m].K;
            int k = i / N, n = i - k * N;
            td.t[m].dst[(size_t)n * K + k] = f2b(td.t[m].src[i]);
            return;
        }
        i -= sz;
    }
}

// ---------------- tiny: spatial_shapes int32 -> fp32 ----------------
__global__ void ss_kernel(const int* __restrict__ ss, float* __restrict__ out_ss)
{
    int i = threadIdx.x;
    if (i < 4) out_ss[i] = (float)ss[i];
}

// ---------------- LDS-staged MFMA GEMM (m97 structure) ----------------
// C = A[M,K] @ B[K,N] + bias (+res) (+relu).  Bt = B^T [N,K] bf16.
// Tile BM x 128, 4 waves as 2x2; wave tile (BM/2) x 64.
// Per K-step (BK=32): global_load_lds stage (linear LDS) -> barrier ->
// ds_read_b128 frags -> MFMA -> barrier.
// AF32: A staged as raw fp32 (16 KB), packed to bf16 on LDS read.
// RESM: 0 none, 1 bf16 residual, 2 fp32 residual.
// VOUT: write head-major value layout [(col>>5)*M + row][32].
template<int BM, bool RELU, int RESM, bool AF32, bool VOUT>
__global__ __launch_bounds__(256) void gemm_lds(
    const ushort_t* __restrict__ A16, const float* __restrict__ A32,
    const ushort_t* __restrict__ Bt, const float* __restrict__ bias,
    const ushort_t* __restrict__ res16, const float* __restrict__ res32,
    ushort_t* __restrict__ Cout, int M, int N, int K)
{
    constexpr int WM = BM / 2;                      // wave tile rows
    constexpr int MR = WM / 16;                     // A frags per wave
    constexpr int ABYTES = BM * 32 * (AF32 ? 4 : 2);
    __shared__ __align__(16) char smem[ABYTES + 128 * 32 * 2];
    ushort_t* lA16 = (ushort_t*)smem;
    float*    lA32 = (float*)smem;
    ushort_t* lB   = (ushort_t*)(smem + ABYTES);

    const int lane = threadIdx.x & 63;
    const int wave = threadIdx.x >> 6;
    const int wm = wave >> 1, wn = wave & 1;
    const int m0 = blockIdx.x * BM;
    const int n0 = blockIdx.y * 128;
    const int r = lane & 15, quad = lane >> 4;

    f32x4 acc[MR][4];
    #pragma unroll
    for (int i = 0; i < MR; i++)
        #pragma unroll
        for (int j = 0; j < 4; j++) acc[i][j] = (f32x4){0.f, 0.f, 0.f, 0.f};

    for (int k0 = 0; k0 < K; k0 += 32) {
        // ---- stage B[n0..n0+127][k0..k0+31] -> lB[128][32] (2 insts/wave) ----
        #pragma unroll
        for (int t = 0; t < 2; t++) {
            int row = wave * 32 + t * 16;
            gload16(Bt + (size_t)(n0 + row + (lane >> 2)) * K + k0 + (lane & 3) * 8,
                    (char*)lB + row * 64);
        }
        // ---- stage A tile ----
        if (AF32) {
            #pragma unroll
            for (int t = 0; t < BM / 32; t++) {
                int row = wave * (BM / 4) + t * 8;
                gload16(A32 + (size_t)(m0 + row + (lane >> 3)) * K + k0 + (lane & 7) * 4,
                        (char*)lA32 + row * 128);
            }
        } else {
            #pragma unroll
            for (int t = 0; t < BM / 64; t++) {
                int row = wave * (BM / 4) + t * 16;
                gload16(A16 + (size_t)(m0 + row + (lane >> 2)) * K + k0 + (lane & 3) * 8,
                        (char*)lA16 + row * 64);
            }
        }
        __syncthreads();   // compiler emits vmcnt(0) drain before the barrier

        short8 af[MR], bf[4];
        #pragma unroll
        for (int i = 0; i < MR; i++) {
            int row = wm * WM + i * 16 + r;
            if (AF32) {
                float4 u = *(const float4*)(lA32 + row * 32 + quad * 8);
                float4 v = *(const float4*)(lA32 + row * 32 + quad * 8 + 4);
                af[i] = pack8(u, v);
            } else {
                af[i] = *(const short8*)(lA16 + row * 32 + quad * 8);
            }
        }
        #pragma unroll
        for (int j = 0; j < 4; j++) {
            int row = wn * 64 + j * 16 + r;
            bf[j] = *(const short8*)(lB + row * 32 + quad * 8);
        }
        #pragma unroll
        for (int i = 0; i < MR; i++)
            #pragma unroll
            for (int j = 0; j < 4; j++)
                acc[i][j] = __builtin_amdgcn_mfma_f32_16x16x32_bf16(af[i], bf[j], acc[i][j], 0, 0, 0);
        __syncthreads();   // protect LDS before next-iteration stage
    }

    float bv[4];
    #pragma unroll
    for (int j = 0; j < 4; j++) bv[j] = bias[n0 + wn * 64 + j * 16 + r];

    #pragma unroll
    for (int i = 0; i < MR; i++) {
        int row = m0 + wm * WM + i * 16 + quad * 4;
        #pragma unroll
        for (int j = 0; j < 4; j++) {
            int col = n0 + wn * 64 + j * 16 + r;
            #pragma unroll
            for (int t = 0; t < 4; t++) {
                float v = acc[i][j][t] + bv[j];
                if (RESM == 1) v += b2f(res16[(size_t)(row + t) * N + col]);
                if (RESM == 2) v += res32[(size_t)(row + t) * N + col];
                if (RELU) v = fmaxf(v, 0.f);
                if (VOUT) {
                    // head-major: [(head)*M + row][32]; head = col>>5, ch = col&31
                    Cout[((size_t)(col >> 5) * (size_t)M + (size_t)(row + t)) * HD_ + (col & 31)] = f2b(v);
                } else {
                    Cout[(size_t)(row + t) * N + col] = f2b(v);
                }
            }
        }
    }
}

// ---------------- reg-direct MFMA GEMM (small-N: off/aw projections) ----------------
template<int WN, bool RELU, int RESM>
__global__ __launch_bounds__(256) void gemm_bf16(
    const ushort_t* __restrict__ A16,
    const ushort_t* __restrict__ Bt, const float* __restrict__ bias,
    ushort_t* __restrict__ Cout, int M, int N, int K)
{
    const int lane = threadIdx.x & 63;
    const int wave = threadIdx.x >> 6;
    const int m0 = blockIdx.x * 256 + wave * 64;
    const int n0 = blockIdx.y * (16 * WN);
    const int r = lane & 15, quad = lane >> 4;

    f32x4 acc[4][WN];
    #pragma unroll
    for (int i = 0; i < 4; i++)
        #pragma unroll
        for (int j = 0; j < WN; j++) acc[i][j] = (f32x4){0.f, 0.f, 0.f, 0.f};

    const ushort_t* Ab16 = A16 + (size_t)(m0 + r) * K + quad * 8;
    const ushort_t* Bbase = Bt + (size_t)(n0 + r) * K + quad * 8;

    for (int k0 = 0; k0 < K; k0 += 64) {
        short8 af0[4], af1[4], b0[WN], b1[WN];
        #pragma unroll
        for (int i = 0; i < 4; i++) {
            af0[i] = *(const short8*)(Ab16 + (size_t)i * 16 * K + k0);
            af1[i] = *(const short8*)(Ab16 + (size_t)i * 16 * K + k0 + 32);
        }
        #pragma unroll
        for (int j = 0; j < WN; j++) {
            b0[j] = *(const short8*)(Bbase + (size_t)j * 16 * K + k0);
            b1[j] = *(const short8*)(Bbase + (size_t)j * 16 * K + k0 + 32);
        }
        #pragma unroll
        for (int i = 0; i < 4; i++)
            #pragma unroll
            for (int j = 0; j < WN; j++)
                acc[i][j] = __builtin_amdgcn_mfma_f32_16x16x32_bf16(af0[i], b0[j], acc[i][j], 0, 0, 0);
        #pragma unroll
        for (int i = 0; i < 4; i++)
            #pragma unroll
            for (int j = 0; j < WN; j++)
                acc[i][j] = __builtin_amdgcn_mfma_f32_16x16x32_bf16(af1[i], b1[j], acc[i][j], 0, 0, 0);
    }

    float bv[WN];
    #pragma unroll
    for (int j = 0; j < WN; j++) bv[j] = bias[n0 + j * 16 + r];

    #pragma unroll
    for (int i = 0; i < 4; i++) {
        int row = m0 + i * 16 + quad * 4;
        #pragma unroll
        for (int j = 0; j < WN; j++) {
            int col = n0 + j * 16 + r;
            #pragma unroll
            for (int t = 0; t < 4; t++) {
                float v = acc[i][j][t] + bv[j];
                if (RELU) v = fmaxf(v, 0.f);
                Cout[(size_t)(row + t) * N + col] = f2b(v);
            }
        }
    }
}

// ---------------- fused softmax + bilinear sampling ----------------
// v layout: [(h*L + l)*Q + pix][HD]  (head-major, 64 B per pixel record)
// 8 lanes per (q,h) group; each lane owns 4 channels (uint2 corner loads).
template<int L>
__global__ __launch_bounds__(256) void sample_kernel(
    const ushort_t* __restrict__ v,    // head-major projected value (bf16)
    const ushort_t* __restrict__ off,  // [Q, NH*L*NP*2] (bf16)
    const ushort_t* __restrict__ aw,   // [Q, NH*L*NP] raw logits (bf16)
    const float*    __restrict__ ref,  // [Q, LC, 2] fp32
    ushort_t* __restrict__ outp)       // [Q, C] bf16
{
    const int t   = blockIdx.x * 256 + threadIdx.x;
    const int g   = t >> 3;            // (q,h) group
    const int sub = t & 7;             // 4-channel slice within head
    const int q   = g >> 3;
    const int h   = g & 7;
    const int P   = L * NP_;

    // ---- softmax over P logits (vectorized bf16 load, normalized in-place) ----
    float w[2 * NP_];
    {
        union { uint4 q4; uint2 q2; ushort_t u[8]; } ab;
        const ushort_t* awp = aw + (size_t)q * (NH_ * P) + h * P;
        if (L == 2) ab.q4 = *(const uint4*)awp;
        else        ab.q2 = *(const uint2*)awp;
        float mx = -1e30f;
        #pragma unroll
        for (int i = 0; i < P; i++) { w[i] = b2f(ab.u[i]); mx = fmaxf(mx, w[i]); }
        float s = 0.f;
        #pragma unroll
        for (int i = 0; i < P; i++) { w[i] = __expf(w[i] - mx); s += w[i]; }
        float inv = 1.f / s;
        #pragma unroll
        for (int i = 0; i < P; i++) w[i] *= inv;
    }

    // ---- offsets (vectorized bf16 load) ----
    float offx[2 * NP_], offy[2 * NP_];
    {
        union { uint4 q4[2]; ushort_t u[16]; } ob;
        const ushort_t* offp = off + (size_t)q * (NH_ * P * 2) + h * (P * 2);
        ob.q4[0] = *(const uint4*)offp;
        if (L == 2) ob.q4[1] = *(const uint4*)(offp + 8);
        #pragma unroll
        for (int i = 0; i < P; i++) { offx[i] = b2f(ob.u[2 * i]); offy[i] = b2f(ob.u[2 * i + 1]); }
    }

    const ushort_t* vh = v + ((size_t)(h * L) * Q_) * HD_ + sub * 4;
    float4 acc = {0.f, 0.f, 0.f, 0.f};

    #pragma unroll
    for (int l = 0; l < L; l++) {
        float rx = ref[((size_t)q * LC_ + l) * 2 + 0] * (float)HW_ - 0.5f;
        float ry = ref[((size_t)q * LC_ + l) * 2 + 1] * (float)HW_ - 0.5f;
        const ushort_t* vl = vh + (size_t)l * ((size_t)Q_ * HD_);
        #pragma unroll
        for (int p = 0; p < NP_; p++) {
            const int ip = l * NP_ + p;
            float x = rx + offx[ip];
            float y = ry + offy[ip];
            x = fminf(fmaxf(x, -1e4f), 1e4f);
            y = fminf(fmaxf(y, -1e4f), 1e4f);
            float xf = floorf(x), yf = floorf(y);
            float tx = x - xf, ty = y - yf;
            int x0 = (int)xf, y0 = (int)yf;
            int x1 = x0 + 1, y1 = y0 + 1;
            int xc0 = min(max(x0, 0), HW_ - 1), xc1 = min(max(x1, 0), HW_ - 1);
            int yc0 = min(max(y0, 0), HW_ - 1), yc1 = min(max(y1, 0), HW_ - 1);
            bool vx0 = (unsigned)x0 < (unsigned)HW_, vx1 = (unsigned)x1 < (unsigned)HW_;
            bool vy0 = (unsigned)y0 < (unsigned)HW_, vy1 = (unsigned)y1 < (unsigned)HW_;

            // fold attention weight + validity into the 4 corner weights
            float aww = w[ip];
            float w00 = (1.f - tx) * (1.f - ty) * aww;
            float w10 = tx * (1.f - ty) * aww;
            float w01 = (1.f - tx) * ty * aww;
            float w11 = tx * ty * aww;
            w00 = (vx0 & vy0) ? w00 : 0.f;
            w10 = (vx1 & vy0) ? w10 : 0.f;
            w01 = (vx0 & vy1) ? w01 : 0.f;
            w11 = (vx1 & vy1) ? w11 : 0.f;

            int r0 = yc0 * HW_, r1 = yc1 * HW_;
            uint2 u00 = *(const uint2*)(vl + (size_t)(r0 + xc0) * HD_);
            uint2 u10 = *(const uint2*)(vl + (size_t)(r0 + xc1) * HD_);
            uint2 u01 = *(const uint2*)(vl + (size_t)(r1 + xc0) * HD_);
            uint2 u11 = *(const uint2*)(vl + (size_t)(r1 + xc1) * HD_);
            float4 c00 = unpk4(u00), c10 = unpk4(u10), c01 = unpk4(u01), c11 = unpk4(u11);

            acc.x += c00.x * w00 + c10.x * w10 + c01.x * w01 + c11.x * w11;
            acc.y += c00.y * w00 + c10.y * w10 + c01.y * w01 + c11.y * w11;
            acc.z += c00.z * w00 + c10.z * w10 + c01.z * w01 + c11.z * w11;
            acc.w += c00.w * w00 + c10.w * w10 + c01.w * w01 + c11.w * w11;
        }
    }

    uint2 o;
    o.x = pack2(acc.x, acc.y);
    o.y = pack2(acc.z, acc.w);
    *(uint2*)(outp + (size_t)q * C_ + h * HD_ + sub * 4) = o;
}

// ---------------- LayerNorm (wave per row of 256) ----------------
// x bf16; gamma/beta fp32. OUT32: y32 fp32 out, else y16 bf16 out.
// optional y2 (bf16) = y + qpos (qpos fp32).
template<bool OUT32>
__global__ __launch_bounds__(256) void ln_kernel(
    const ushort_t* __restrict__ x, const float* __restrict__ g,
    const float* __restrict__ b, ushort_t* __restrict__ y16,
    float* __restrict__ y32,
    const float* __restrict__ qpos, ushort_t* __restrict__ y2)
{
    const int lane = threadIdx.x & 63;
    const int wave = threadIdx.x >> 6;
    const size_t row = (size_t)blockIdx.x * 4 + wave;
    const size_t base = row * C_ + lane * 4;

    uint2 xv = *(const uint2*)(x + base);
    float f0 = b2f((ushort_t)(xv.x & 0xFFFF)), f1 = b2f((ushort_t)(xv.x >> 16));
    float f2 = b2f((ushort_t)(xv.y & 0xFFFF)), f3 = b2f((ushort_t)(xv.y >> 16));
    float s  = f0 + f1 + f2 + f3;
    float sq = f0 * f0 + f1 * f1 + f2 * f2 + f3 * f3;
    #pragma unroll
    for (int m = 1; m < 64; m <<= 1) { s += __shfl_xor(s, m, 64); sq += __shfl_xor(sq, m, 64); }
    float mean = s * (1.f / 256.f);
    float var  = sq * (1.f / 256.f) - mean * mean;
    float rinv = rsqrtf(fmaxf(var, 0.f) + 1e-5f);

    float4 gv = *(const float4*)(g + lane * 4);
    float4 bv = *(const float4*)(b + lane * 4);
    float o0 = (f0 - mean) * rinv * gv.x + bv.x;
    float o1 = (f1 - mean) * rinv * gv.y + bv.y;
    float o2 = (f2 - mean) * rinv * gv.z + bv.z;
    float o3 = (f3 - mean) * rinv * gv.w + bv.w;

    if (OUT32) {
        float4 o; o.x = o0; o.y = o1; o.z = o2; o.w = o3;
        *(float4*)(y32 + base) = o;
    } else {
        uint2 ov; ov.x = pack2(o0, o1); ov.y = pack2(o2, o3);
        *(uint2*)(y16 + base) = ov;
    }

    if (y2) {
        float4 pv = *(const float4*)(qpos + base);
        uint2 o2v;
        o2v.x = pack2(o0 + pv.x, o1 + pv.y);
        o2v.y = pack2(o2 + pv.z, o3 + pv.w);
        *(uint2*)(y2 + base) = o2v;
    }
}

// ---------------- host ----------------
extern "C" void kernel_launch(void* const* d_in, const int* in_sizes, int n_in,
                              void* d_out, int out_size, void* d_ws, size_t ws_size,
                              hipStream_t stream)
{
    const float* query = (const float*)d_in[0];
    const float* qpos  = (const float*)d_in[1];
    const float* value = (const float*)d_in[2];
    const float* ref   = (const float*)d_in[3];
    const int*   ss    = (const int*)d_in[4];
    const float* sa_off_w = (const float*)d_in[5];
    const float* sa_off_b = (const float*)d_in[6];
    const float* sa_aw_w  = (const float*)d_in[7];
    const float* sa_aw_b  = (const float*)d_in[8];
    const float* sa_vp_w  = (const float*)d_in[9];
    const float* sa_vp_b  = (const float*)d_in[10];
    const float* sa_op_w  = (const float*)d_in[11];
    const float* sa_op_b  = (const float*)d_in[12];
    const float* ca_off_w = (const float*)d_in[13];
    const float* ca_off_b = (const float*)d_in[14];
    const float* ca_aw_w  = (const float*)d_in[15];
    const float* ca_aw_b  = (const float*)d_in[16];
    const float* ca_vp_w  = (const float*)d_in[17];
    const float* ca_vp_b  = (const float*)d_in[18];
    const float* ca_op_w  = (const float*)d_in[19];
    const float* ca_op_b  = (const float*)d_in[20];
    const float* ffn_w1   = (const float*)d_in[21];
    const float* ffn_b1   = (const float*)d_in[22];
    const float* ffn_w2   = (const float*)d_in[23];
    const float* ffn_b2   = (const float*)d_in[24];
    const float* ln1_g = (const float*)d_in[25];
    const float* ln1_b = (const float*)d_in[26];
    const float* ln2_g = (const float*)d_in[27];
    const float* ln2_b = (const float*)d_in[28];
    const float* ln3_g = (const float*)d_in[29];
    const float* ln3_b = (const float*)d_in[30];

    // ---- final output layout (fp32) ----
    float* outf    = (float*)d_out;
    float* out_q   = outf;                            // [Q,C]
    float* out_qp  = outf + QC;                       // [Q,C]
    float* out_val = outf + 2 * (size_t)QC;           // [2Q,C]
    float* out_ref = outf + 4 * (size_t)QC;           // [Q,LC,2]
    float* out_ss  = outf + 4 * (size_t)QC + REFN;    // [4]

    // ---- d_out doubles as bf16 body scratch (all dead before final writes) ----
    ushort_t* dsc    = (ushort_t*)d_out;
    ushort_t* vbuf   = dsc;                           // 2QC bf16 (head-major value)
    ushort_t* tmp    = dsc + 2 * (size_t)QC;          // QC bf16
    ushort_t* offb   = dsc + 3 * (size_t)QC;          // Q*128
    ushort_t* awb    = dsc + 3 * (size_t)QC + (size_t)Q_ * 128;  // Q*64
    ushort_t* hidden = dsc;                           // Q*1024 bf16

    // ---- workspace: ~42.8 MB bf16 ----
    char* base = (char*)d_ws;
    size_t offbyte = 0;
    auto alloc = [&](size_t elems) -> ushort_t* {
        ushort_t* p = (ushort_t*)(base + offbyte);
        offbyte += ((elems * 2 + 255) / 256) * 256;
        return p;
    };
    ushort_t* wt_sa_off = alloc(256 * 64);
    ushort_t* wt_sa_aw  = alloc(256 * 32);
    ushort_t* wt_sa_vp  = alloc(256 * 256);
    ushort_t* wt_sa_op  = alloc(256 * 256);
    ushort_t* wt_ca_off = alloc(256 * 128);
    ushort_t* wt_ca_aw  = alloc(256 * 64);
    ushort_t* wt_ca_vp  = alloc(256 * 256);
    ushort_t* wt_ca_op  = alloc(256 * 256);
    ushort_t* wt_ffn1   = alloc(256 * 1024);
    ushort_t* wt_ffn2   = alloc(1024 * 256);
    ushort_t* qpq  = alloc(QC);     // bf16(q+pos), then bf16(q1+pos)
    ushort_t* attn = alloc(QC);     // sampled attention out; later q2 (LN2 out)
    ushort_t* q1   = alloc(QC);     // LN1 out; later FFN2 out
    ushort_t* q2   = attn;          // LN2 out overlays dead attn

    TAll td;
    const float* srcs[10] = {sa_off_w, sa_aw_w, sa_vp_w, sa_op_w, ca_off_w,
                             ca_aw_w, ca_vp_w, ca_op_w, ffn_w1, ffn_w2};
    ushort_t* dsts[10] = {wt_sa_off, wt_sa_aw, wt_sa_vp, wt_sa_op, wt_ca_off,
                          wt_ca_aw, wt_ca_vp, wt_ca_op, wt_ffn1, wt_ffn2};
    int Ks[10] = {256, 256, 256, 256, 256, 256, 256, 256, 256, 1024};
    int Ns[10] = {64, 32, 256, 256, 128, 64, 256, 256, 1024, 256};
    for (int m = 0; m < 10; m++) { td.t[m] = {srcs[m], dsts[m], Ks[m], Ns[m]}; }

    // 1. prologue
    prologue_kernel<<<(PRO_TOTAL + 255) / 256, 256, 0, stream>>>(query, qpos, qpq, td);

    // ---- self-attention (L=1, value = raw fp32 query) ----
    gemm_lds<64, false, 0, true, true><<<dim3(Q_ / 64, 2), 256, 0, stream>>>(
        nullptr, query, wt_sa_vp, sa_vp_b, nullptr, nullptr, vbuf, Q_, 256, 256);
    gemm_bf16<4, false, 0><<<dim3(Q_ / 256, 1), 256, 0, stream>>>(
        qpq, wt_sa_off, sa_off_b, offb, Q_, 64, 256);
    gemm_bf16<2, false, 0><<<dim3(Q_ / 256, 1), 256, 0, stream>>>(
        qpq, wt_sa_aw, sa_aw_b, awb, Q_, 32, 256);
    sample_kernel<1><<<(Q_ * NH_) / 32, 256, 0, stream>>>(vbuf, offb, awb, ref, attn);
    gemm_lds<64, false, 2, false, false><<<dim3(Q_ / 64, 2), 256, 0, stream>>>(
        attn, nullptr, wt_sa_op, sa_op_b, nullptr, query, tmp, Q_, 256, 256);
    ln_kernel<false><<<Q_ / 4, 256, 0, stream>>>(tmp, ln1_g, ln1_b, q1, nullptr, qpos, qpq);

    // ---- cross-attention (L=2, value = raw fp32 value) ----
    gemm_lds<64, false, 0, true, true><<<dim3(2 * Q_ / 64, 2), 256, 0, stream>>>(
        nullptr, value, wt_ca_vp, ca_vp_b, nullptr, nullptr, vbuf, 2 * Q_, 256, 256);
    gemm_lds<64, false, 0, false, false><<<dim3(Q_ / 64, 1), 256, 0, stream>>>(
        qpq, nullptr, wt_ca_off, ca_off_b, nullptr, nullptr, offb, Q_, 128, 256);
    gemm_bf16<4, false, 0><<<dim3(Q_ / 256, 1), 256, 0, stream>>>(
        qpq, wt_ca_aw, ca_aw_b, awb, Q_, 64, 256);
    sample_kernel<2><<<(Q_ * NH_) / 32, 256, 0, stream>>>(vbuf, offb, awb, ref, attn);
    gemm_lds<64, false, 1, false, false><<<dim3(Q_ / 64, 2), 256, 0, stream>>>(
        attn, nullptr, wt_ca_op, ca_op_b, q1, nullptr, tmp, Q_, 256, 256);
    ln_kernel<false><<<Q_ / 4, 256, 0, stream>>>(tmp, ln2_g, ln2_b, q2, nullptr, nullptr, nullptr);

    // ---- FFN ----
    gemm_lds<128, true, 0, false, false><<<dim3(Q_ / 128, 8), 256, 0, stream>>>(
        q2, nullptr, wt_ffn1, ffn_b1, nullptr, nullptr, hidden, Q_, 1024, 256);
    gemm_lds<64, false, 1, false, false><<<dim3(Q_ / 64, 2), 256, 0, stream>>>(
        hidden, nullptr, wt_ffn2, ffn_b2, q2, nullptr, q1, Q_, 256, 1024);
    // LN3 -> fp32 final output (overlays dead hidden region)
    ln_kernel<true><<<Q_ / 4, 256, 0, stream>>>(q1, ln3_g, ln3_b, nullptr, out_q, nullptr, nullptr);

    // ---- passthrough outputs: pure fp32 D2D copies (scratch regions now dead) ----
    hipMemcpyAsync(out_qp,  qpos,  (size_t)QC * 4,  hipMemcpyDeviceToDevice, stream);
    hipMemcpyAsync(out_val, value, (size_t)VC * 4,  hipMemcpyDeviceToDevice, stream);
    hipMemcpyAsync(out_ref, ref,   (size_t)REFN * 4, hipMemcpyDeviceToDevice, stream);
    ss_kernel<<<1, 64, 0, stream>>>(ss, out_ss);

    (void)in_sizes; (void)n_in; (void)out_size; (void)ws_size;
}

// Round 10
// 492.528 us; speedup vs baseline: 1.3883x; 1.0341x over previous
//
#include <hip/hip_runtime.h>

// ---------------- problem constants ----------------
#define Q_   25600
#define C_   256
#define NH_  8
#define HD_  32
#define NP_  4
#define LC_  2
#define HW_  160          // H == W == 160

#define QC   (Q_ * C_)            // 6,553,600
#define VC   (2 * QC)             // 13,107,200
#define REFN (Q_ * LC_ * 2)       // 102,400

typedef unsigned short ushort_t;
typedef __attribute__((ext_vector_type(8))) short short8;
typedef __attribute__((ext_vector_type(4))) float f32x4;

// ---------------- bf16 helpers ----------------
__device__ __forceinline__ float b2f(ushort_t u) {
    union { unsigned int u32; float f; } c; c.u32 = ((unsigned int)u) << 16; return c.f;
}
__device__ __forceinline__ ushort_t f2b(float f) {
    union { float f; unsigned int u32; } c; c.f = f;
    unsigned int u = c.u32;
    return (ushort_t)((u + 0x7FFFu + ((u >> 16) & 1u)) >> 16);
}
__device__ __forceinline__ unsigned int pack2(float lo, float hi){
    return (unsigned int)f2b(lo) | ((unsigned int)f2b(hi) << 16);
}
__device__ __forceinline__ short8 pack8(float4 a, float4 b){
    union { short8 s; ushort_t u[8]; } r;
    r.u[0]=f2b(a.x); r.u[1]=f2b(a.y); r.u[2]=f2b(a.z); r.u[3]=f2b(a.w);
    r.u[4]=f2b(b.x); r.u[5]=f2b(b.y); r.u[6]=f2b(b.z); r.u[7]=f2b(b.w);
    return r.s;
}
__device__ __forceinline__ float uasf(unsigned int u){
    union { unsigned int u32; float f; } c; c.u32 = u; return c.f;
}
// unpack 4 bf16 (packed in uint2) -> 4 floats
__device__ __forceinline__ float4 unpk4(uint2 u){
    float4 r;
    r.x = uasf(u.x << 16); r.y = uasf(u.x & 0xFFFF0000u);
    r.z = uasf(u.y << 16); r.w = uasf(u.y & 0xFFFF0000u);
    return r;
}

// async global->LDS, 16 B per lane; LDS dest = wave-uniform base + lane*16
__device__ __forceinline__ void gload16(const void* g, void* l) {
    __builtin_amdgcn_global_load_lds(
        (const __attribute__((address_space(1))) void*)(uintptr_t)(g),
        (__attribute__((address_space(3))) void*)(uintptr_t)(l), 16, 0, 0);
}

// ---------------- prologue: qpq = bf16(query+qpos) + weight transposes (fp32->bf16) ----------------
struct TDesc { const float* src; ushort_t* dst; int K; int N; };
struct TAll  { TDesc t[10]; };

#define QC4   (QC / 4)        // 1,638,400
#define TRANS_TOTAL 860160
#define PRO_TOTAL (QC4 + TRANS_TOTAL)

__global__ __launch_bounds__(256) void prologue_kernel(
    const float* __restrict__ query, const float* __restrict__ qpos,
    ushort_t* __restrict__ qpq, TAll td)
{
    int i = blockIdx.x * 256 + threadIdx.x;
    if (i < QC4) {
        float4 qv = ((const float4*)query)[i];
        float4 pv = ((const float4*)qpos)[i];
        uint2 o;
        o.x = pack2(qv.x + pv.x, qv.y + pv.y);
        o.y = pack2(qv.z + pv.z, qv.w + pv.w);
        ((uint2*)qpq)[i] = o;
        return;
    }
    i -= QC4;
    #pragma unroll 1
    for (int m = 0; m < 10; m++) {
        int sz = td.t[m].K * td.t[m].N;
        if (i < sz) {
            int N = td.t[m].N, K = td.t[m].K;
            int k = i / N, n = i - k * N;
            td.t[m].dst[(size_t)n * K + k] = f2b(td.t[m].src[i]);
            return;
        }
        i -= sz;
    }
}

// ---------------- prep: ss int32->fp32 + concatenated off/aw bias vectors ----------------
__global__ void prep_kernel(const int* __restrict__ ss, float* __restrict__ out_ss,
                            const float* __restrict__ sa_off_b, const float* __restrict__ sa_aw_b,
                            const float* __restrict__ ca_off_b, const float* __restrict__ ca_aw_b,
                            float* __restrict__ cb_sa, float* __restrict__ cb_ca)
{
    int i = threadIdx.x;
    if (i < 4)   out_ss[i] = (float)ss[i];
    if (i < 96)  cb_sa[i] = (i < 64) ? sa_off_b[i] : sa_aw_b[i - 64];
    if (i < 192) cb_ca[i] = (i < 128) ? ca_off_b[i] : ca_aw_b[i - 128];
}

// ---------------- LDS-staged MFMA GEMM (m97 structure, BK=64 as 2x32 sub-stages) ----------------
// C = A[M,K] @ B[K,N] + bias (+res) (+relu).  Bt = B^T [N,K] bf16.
// Tile BM x 128, 4 waves as 2x2; wave tile (BM/2) x 64.
// Per K-step (BK=64): stage both 32-col sub-tiles (linear 64B-row LDS, same
// geometry as the verified BK=32 version) -> ONE barrier -> ds_read frags for
// both sub-steps -> 2x MFMA block -> barrier.  Halves barrier/vmcnt stalls.
// AF32: A staged as raw fp32, packed to bf16 on LDS read.
// RESM: 0 none, 1 bf16 residual, 2 fp32 residual.
// VOUT: write head-major value layout [(col>>5)*M + row][32].
template<int BM, bool RELU, int RESM, bool AF32, bool VOUT>
__global__ __launch_bounds__(256) void gemm_lds(
    const ushort_t* __restrict__ A16, const float* __restrict__ A32,
    const ushort_t* __restrict__ Bt, const float* __restrict__ bias,
    const ushort_t* __restrict__ res16, const float* __restrict__ res32,
    ushort_t* __restrict__ Cout, int M, int N, int K)
{
    constexpr int WM = BM / 2;                      // wave tile rows
    constexpr int MR = WM / 16;                     // A frags per wave
    constexpr int ASUB = BM * 32 * (AF32 ? 4 : 2);  // bytes per 32-col A sub-tile
    constexpr int BSUB = 128 * 32 * 2;              // bytes per 32-col B sub-tile
    __shared__ __align__(16) char smem[2 * ASUB + 2 * BSUB];
    char* lA = smem;                                // [2][BM][32] (bf16 or fp32)
    char* lB = smem + 2 * ASUB;                     // [2][128][32] bf16

    const int lane = threadIdx.x & 63;
    const int wave = threadIdx.x >> 6;
    const int wm = wave >> 1, wn = wave & 1;
    const int m0 = blockIdx.x * BM;
    const int n0 = blockIdx.y * 128;
    const int r = lane & 15, quad = lane >> 4;

    f32x4 acc[MR][4];
    #pragma unroll
    for (int i = 0; i < MR; i++)
        #pragma unroll
        for (int j = 0; j < 4; j++) acc[i][j] = (f32x4){0.f, 0.f, 0.f, 0.f};

    for (int k0 = 0; k0 < K; k0 += 64) {
        // ---- stage B: 2 sub-tiles of [128][32] bf16 (64-B rows) ----
        #pragma unroll
        for (int s = 0; s < 2; s++)
            #pragma unroll
            for (int t = 0; t < 2; t++) {
                int row = wave * 32 + t * 16;
                gload16(Bt + (size_t)(n0 + row + (lane >> 2)) * K + k0 + s * 32 + (lane & 3) * 8,
                        lB + s * BSUB + row * 64);
            }
        // ---- stage A: 2 sub-tiles ----
        if (AF32) {
            #pragma unroll
            for (int s = 0; s < 2; s++)
                #pragma unroll
                for (int t = 0; t < BM / 32; t++) {
                    int row = wave * (BM / 4) + t * 8;
                    gload16(A32 + (size_t)(m0 + row + (lane >> 3)) * K + k0 + s * 32 + (lane & 7) * 4,
                            lA + s * ASUB + row * 128);
                }
        } else {
            #pragma unroll
            for (int s = 0; s < 2; s++)
                #pragma unroll
                for (int t = 0; t < BM / 64; t++) {
                    int row = wave * (BM / 4) + t * 16;
                    gload16(A16 + (size_t)(m0 + row + (lane >> 2)) * K + k0 + s * 32 + (lane & 3) * 8,
                            lA + s * ASUB + row * 64);
                }
        }
        __syncthreads();   // compiler emits vmcnt(0) drain before the barrier

        short8 af[2][MR], bf[2][4];
        #pragma unroll
        for (int s = 0; s < 2; s++) {
            #pragma unroll
            for (int i = 0; i < MR; i++) {
                int row = wm * WM + i * 16 + r;
                if (AF32) {
                    const float* p = (const float*)(lA + s * ASUB) + row * 32 + quad * 8;
                    float4 u = *(const float4*)p;
                    float4 v = *(const float4*)(p + 4);
                    af[s][i] = pack8(u, v);
                } else {
                    af[s][i] = *(const short8*)((const ushort_t*)(lA + s * ASUB) + row * 32 + quad * 8);
                }
            }
            #pragma unroll
            for (int j = 0; j < 4; j++) {
                int row = wn * 64 + j * 16 + r;
                bf[s][j] = *(const short8*)((const ushort_t*)(lB + s * BSUB) + row * 32 + quad * 8);
            }
        }
        #pragma unroll
        for (int s = 0; s < 2; s++)
            #pragma unroll
            for (int i = 0; i < MR; i++)
                #pragma unroll
                for (int j = 0; j < 4; j++)
                    acc[i][j] = __builtin_amdgcn_mfma_f32_16x16x32_bf16(af[s][i], bf[s][j], acc[i][j], 0, 0, 0);
        __syncthreads();   // protect LDS before next-iteration stage
    }

    float bv[4];
    #pragma unroll
    for (int j = 0; j < 4; j++) bv[j] = bias[n0 + wn * 64 + j * 16 + r];

    #pragma unroll
    for (int i = 0; i < MR; i++) {
        int row = m0 + wm * WM + i * 16 + quad * 4;
        #pragma unroll
        for (int j = 0; j < 4; j++) {
            int col = n0 + wn * 64 + j * 16 + r;
            #pragma unroll
            for (int t = 0; t < 4; t++) {
                float v = acc[i][j][t] + bv[j];
                if (RESM == 1) v += b2f(res16[(size_t)(row + t) * N + col]);
                if (RESM == 2) v += res32[(size_t)(row + t) * N + col];
                if (RELU) v = fmaxf(v, 0.f);
                if (VOUT) {
                    // head-major: [(head)*M + row][32]; head = col>>5, ch = col&31
                    Cout[((size_t)(col >> 5) * (size_t)M + (size_t)(row + t)) * HD_ + (col & 31)] = f2b(v);
                } else {
                    Cout[(size_t)(row + t) * N + col] = f2b(v);
                }
            }
        }
    }
}

// ---------------- reg-direct MFMA GEMM (small-N: fused off+aw projections) ----------------
template<int WN, bool RELU, int RESM>
__global__ __launch_bounds__(256) void gemm_bf16(
    const ushort_t* __restrict__ A16,
    const ushort_t* __restrict__ Bt, const float* __restrict__ bias,
    ushort_t* __restrict__ Cout, int M, int N, int K)
{
    const int lane = threadIdx.x & 63;
    const int wave = threadIdx.x >> 6;
    const int m0 = blockIdx.x * 256 + wave * 64;
    const int n0 = blockIdx.y * (16 * WN);
    const int r = lane & 15, quad = lane >> 4;

    f32x4 acc[4][WN];
    #pragma unroll
    for (int i = 0; i < 4; i++)
        #pragma unroll
        for (int j = 0; j < WN; j++) acc[i][j] = (f32x4){0.f, 0.f, 0.f, 0.f};

    const ushort_t* Ab16 = A16 + (size_t)(m0 + r) * K + quad * 8;
    const ushort_t* Bbase = Bt + (size_t)(n0 + r) * K + quad * 8;

    for (int k0 = 0; k0 < K; k0 += 64) {
        short8 af0[4], af1[4], b0[WN], b1[WN];
        #pragma unroll
        for (int i = 0; i < 4; i++) {
            af0[i] = *(const short8*)(Ab16 + (size_t)i * 16 * K + k0);
            af1[i] = *(const short8*)(Ab16 + (size_t)i * 16 * K + k0 + 32);
        }
        #pragma unroll
        for (int j = 0; j < WN; j++) {
            b0[j] = *(const short8*)(Bbase + (size_t)j * 16 * K + k0);
            b1[j] = *(const short8*)(Bbase + (size_t)j * 16 * K + k0 + 32);
        }
        #pragma unroll
        for (int i = 0; i < 4; i++)
            #pragma unroll
            for (int j = 0; j < WN; j++)
                acc[i][j] = __builtin_amdgcn_mfma_f32_16x16x32_bf16(af0[i], b0[j], acc[i][j], 0, 0, 0);
        #pragma unroll
        for (int i = 0; i < 4; i++)
            #pragma unroll
            for (int j = 0; j < WN; j++)
                acc[i][j] = __builtin_amdgcn_mfma_f32_16x16x32_bf16(af1[i], b1[j], acc[i][j], 0, 0, 0);
    }

    float bv[WN];
    #pragma unroll
    for (int j = 0; j < WN; j++) bv[j] = bias[n0 + j * 16 + r];

    #pragma unroll
    for (int i = 0; i < 4; i++) {
        int row = m0 + i * 16 + quad * 4;
        #pragma unroll
        for (int j = 0; j < WN; j++) {
            int col = n0 + j * 16 + r;
            #pragma unroll
            for (int t = 0; t < 4; t++) {
                float v = acc[i][j][t] + bv[j];
                if (RELU) v = fmaxf(v, 0.f);
                Cout[(size_t)(row + t) * N + col] = f2b(v);
            }
        }
    }
}

// ---------------- fused softmax + bilinear sampling ----------------
// v layout: [(h*L + l)*Q + pix][HD]  (head-major, 64 B per pixel record)
// cb: combined [Q][off(NH*P*2) ++ aw(NH*P)] bf16 from the fused projection GEMM.
// 8 lanes per (q,h) group; each lane owns 4 channels (uint2 corner loads).
template<int L>
__global__ __launch_bounds__(256) void sample_kernel(
    const ushort_t* __restrict__ v,    // head-major projected value (bf16)
    const ushort_t* __restrict__ cb,   // [Q, NH*L*NP*3] combined off+aw (bf16)
    const float*    __restrict__ ref,  // [Q, LC, 2] fp32
    ushort_t* __restrict__ outp)       // [Q, C] bf16
{
    const int t   = blockIdx.x * 256 + threadIdx.x;
    const int g   = t >> 3;            // (q,h) group
    const int sub = t & 7;             // 4-channel slice within head
    const int q   = g >> 3;
    const int h   = g & 7;
    const int P   = L * NP_;
    const int STR = NH_ * P * 3;       // 96 (L=1) or 192 (L=2)

    // ---- softmax over P logits (vectorized bf16 load, normalized in-place) ----
    float w[2 * NP_];
    {
        union { uint4 q4; uint2 q2; ushort_t u[8]; } ab;
        const ushort_t* awp = cb + (size_t)q * STR + NH_ * P * 2 + h * P;
        if (L == 2) ab.q4 = *(const uint4*)awp;
        else        ab.q2 = *(const uint2*)awp;
        float mx = -1e30f;
        #pragma unroll
        for (int i = 0; i < P; i++) { w[i] = b2f(ab.u[i]); mx = fmaxf(mx, w[i]); }
        float s = 0.f;
        #pragma unroll
        for (int i = 0; i < P; i++) { w[i] = __expf(w[i] - mx); s += w[i]; }
        float inv = 1.f / s;
        #pragma unroll
        for (int i = 0; i < P; i++) w[i] *= inv;
    }

    // ---- offsets (vectorized bf16 load) ----
    float offx[2 * NP_], offy[2 * NP_];
    {
        union { uint4 q4[2]; ushort_t u[16]; } ob;
        const ushort_t* offp = cb + (size_t)q * STR + h * (P * 2);
        ob.q4[0] = *(const uint4*)offp;
        if (L == 2) ob.q4[1] = *(const uint4*)(offp + 8);
        #pragma unroll
        for (int i = 0; i < P; i++) { offx[i] = b2f(ob.u[2 * i]); offy[i] = b2f(ob.u[2 * i + 1]); }
    }

    const ushort_t* vh = v + ((size_t)(h * L) * Q_) * HD_ + sub * 4;
    float4 acc = {0.f, 0.f, 0.f, 0.f};

    #pragma unroll
    for (int l = 0; l < L; l++) {
        float rx = ref[((size_t)q * LC_ + l) * 2 + 0] * (float)HW_ - 0.5f;
        float ry = ref[((size_t)q * LC_ + l) * 2 + 1] * (float)HW_ - 0.5f;
        const ushort_t* vl = vh + (size_t)l * ((size_t)Q_ * HD_);
        #pragma unroll
        for (int p = 0; p < NP_; p++) {
            const int ip = l * NP_ + p;
            float x = rx + offx[ip];
            float y = ry + offy[ip];
            x = fminf(fmaxf(x, -1e4f), 1e4f);
            y = fminf(fmaxf(y, -1e4f), 1e4f);
            float xf = floorf(x), yf = floorf(y);
            float tx = x - xf, ty = y - yf;
            int x0 = (int)xf, y0 = (int)yf;
            int x1 = x0 + 1, y1 = y0 + 1;
            int xc0 = min(max(x0, 0), HW_ - 1), xc1 = min(max(x1, 0), HW_ - 1);
            int yc0 = min(max(y0, 0), HW_ - 1), yc1 = min(max(y1, 0), HW_ - 1);
            bool vx0 = (unsigned)x0 < (unsigned)HW_, vx1 = (unsigned)x1 < (unsigned)HW_;
            bool vy0 = (unsigned)y0 < (unsigned)HW_, vy1 = (unsigned)y1 < (unsigned)HW_;

            // fold attention weight + validity into the 4 corner weights
            float aww = w[ip];
            float w00 = (1.f - tx) * (1.f - ty) * aww;
            float w10 = tx * (1.f - ty) * aww;
            float w01 = (1.f - tx) * ty * aww;
            float w11 = tx * ty * aww;
            w00 = (vx0 & vy0) ? w00 : 0.f;
            w10 = (vx1 & vy0) ? w10 : 0.f;
            w01 = (vx0 & vy1) ? w01 : 0.f;
            w11 = (vx1 & vy1) ? w11 : 0.f;

            int r0 = yc0 * HW_, r1 = yc1 * HW_;
            uint2 u00 = *(const uint2*)(vl + (size_t)(r0 + xc0) * HD_);
            uint2 u10 = *(const uint2*)(vl + (size_t)(r0 + xc1) * HD_);
            uint2 u01 = *(const uint2*)(vl + (size_t)(r1 + xc0) * HD_);
            uint2 u11 = *(const uint2*)(vl + (size_t)(r1 + xc1) * HD_);
            float4 c00 = unpk4(u00), c10 = unpk4(u10), c01 = unpk4(u01), c11 = unpk4(u11);

            acc.x += c00.x * w00 + c10.x * w10 + c01.x * w01 + c11.x * w11;
            acc.y += c00.y * w00 + c10.y * w10 + c01.y * w01 + c11.y * w11;
            acc.z += c00.z * w00 + c10.z * w10 + c01.z * w01 + c11.z * w11;
            acc.w += c00.w * w00 + c10.w * w10 + c01.w * w01 + c11.w * w11;
        }
    }

    uint2 o;
    o.x = pack2(acc.x, acc.y);
    o.y = pack2(acc.z, acc.w);
    *(uint2*)(outp + (size_t)q * C_ + h * HD_ + sub * 4) = o;
}

// ---------------- LayerNorm (wave per row of 256) ----------------
// x bf16; gamma/beta fp32. OUT32: y32 fp32 out, else y16 bf16 out.
// optional y2 (bf16) = y + qpos (qpos fp32).
template<bool OUT32>
__global__ __launch_bounds__(256) void ln_kernel(
    const ushort_t* __restrict__ x, const float* __restrict__ g,
    const float* __restrict__ b, ushort_t* __restrict__ y16,
    float* __restrict__ y32,
    const float* __restrict__ qpos, ushort_t* __restrict__ y2)
{
    const int lane = threadIdx.x & 63;
    const int wave = threadIdx.x >> 6;
    const size_t row = (size_t)blockIdx.x * 4 + wave;
    const size_t base = row * C_ + lane * 4;

    uint2 xv = *(const uint2*)(x + base);
    float f0 = b2f((ushort_t)(xv.x & 0xFFFF)), f1 = b2f((ushort_t)(xv.x >> 16));
    float f2 = b2f((ushort_t)(xv.y & 0xFFFF)), f3 = b2f((ushort_t)(xv.y >> 16));
    float s  = f0 + f1 + f2 + f3;
    float sq = f0 * f0 + f1 * f1 + f2 * f2 + f3 * f3;
    #pragma unroll
    for (int m = 1; m < 64; m <<= 1) { s += __shfl_xor(s, m, 64); sq += __shfl_xor(sq, m, 64); }
    float mean = s * (1.f / 256.f);
    float var  = sq * (1.f / 256.f) - mean * mean;
    float rinv = rsqrtf(fmaxf(var, 0.f) + 1e-5f);

    float4 gv = *(const float4*)(g + lane * 4);
    float4 bv = *(const float4*)(b + lane * 4);
    float o0 = (f0 - mean) * rinv * gv.x + bv.x;
    float o1 = (f1 - mean) * rinv * gv.y + bv.y;
    float o2 = (f2 - mean) * rinv * gv.z + bv.z;
    float o3 = (f3 - mean) * rinv * gv.w + bv.w;

    if (OUT32) {
        float4 o; o.x = o0; o.y = o1; o.z = o2; o.w = o3;
        *(float4*)(y32 + base) = o;
    } else {
        uint2 ov; ov.x = pack2(o0, o1); ov.y = pack2(o2, o3);
        *(uint2*)(y16 + base) = ov;
    }

    if (y2) {
        float4 pv = *(const float4*)(qpos + base);
        uint2 o2v;
        o2v.x = pack2(o0 + pv.x, o1 + pv.y);
        o2v.y = pack2(o2 + pv.z, o3 + pv.w);
        *(uint2*)(y2 + base) = o2v;
    }
}

// ---------------- host ----------------
extern "C" void kernel_launch(void* const* d_in, const int* in_sizes, int n_in,
                              void* d_out, int out_size, void* d_ws, size_t ws_size,
                              hipStream_t stream)
{
    const float* query = (const float*)d_in[0];
    const float* qpos  = (const float*)d_in[1];
    const float* value = (const float*)d_in[2];
    const float* ref   = (const float*)d_in[3];
    const int*   ss    = (const int*)d_in[4];
    const float* sa_off_w = (const float*)d_in[5];
    const float* sa_off_b = (const float*)d_in[6];
    const float* sa_aw_w  = (const float*)d_in[7];
    const float* sa_aw_b  = (const float*)d_in[8];
    const float* sa_vp_w  = (const float*)d_in[9];
    const float* sa_vp_b  = (const float*)d_in[10];
    const float* sa_op_w  = (const float*)d_in[11];
    const float* sa_op_b  = (const float*)d_in[12];
    const float* ca_off_w = (const float*)d_in[13];
    const float* ca_off_b = (const float*)d_in[14];
    const float* ca_aw_w  = (const float*)d_in[15];
    const float* ca_aw_b  = (const float*)d_in[16];
    const float* ca_vp_w  = (const float*)d_in[17];
    const float* ca_vp_b  = (const float*)d_in[18];
    const float* ca_op_w  = (const float*)d_in[19];
    const float* ca_op_b  = (const float*)d_in[20];
    const float* ffn_w1   = (const float*)d_in[21];
    const float* ffn_b1   = (const float*)d_in[22];
    const float* ffn_w2   = (const float*)d_in[23];
    const float* ffn_b2   = (const float*)d_in[24];
    const float* ln1_g = (const float*)d_in[25];
    const float* ln1_b = (const float*)d_in[26];
    const float* ln2_g = (const float*)d_in[27];
    const float* ln2_b = (const float*)d_in[28];
    const float* ln3_g = (const float*)d_in[29];
    const float* ln3_b = (const float*)d_in[30];

    // ---- final output layout (fp32) ----
    float* outf    = (float*)d_out;
    float* out_q   = outf;                            // [Q,C]
    float* out_qp  = outf + QC;                       // [Q,C]
    float* out_val = outf + 2 * (size_t)QC;           // [2Q,C]
    float* out_ref = outf + 4 * (size_t)QC;           // [Q,LC,2]
    float* out_ss  = outf + 4 * (size_t)QC + REFN;    // [4]

    // ---- d_out doubles as bf16 body scratch (all dead before final writes) ----
    ushort_t* dsc    = (ushort_t*)d_out;
    ushort_t* vbuf   = dsc;                           // 2QC bf16 (head-major value)
    ushort_t* tmp    = dsc + 2 * (size_t)QC;          // QC bf16
    ushort_t* cqa    = dsc + 3 * (size_t)QC;          // Q*192 bf16 max (combined off+aw)
    ushort_t* hidden = dsc;                           // Q*1024 bf16

    // ---- workspace: ~42.8 MB bf16 ----
    char* base = (char*)d_ws;
    size_t offbyte = 0;
    auto alloc = [&](size_t elems) -> ushort_t* {
        ushort_t* p = (ushort_t*)(base + offbyte);
        offbyte += ((elems * 2 + 255) / 256) * 256;
        return p;
    };
    // NOTE: wt_sa_off/wt_sa_aw and wt_ca_off/wt_ca_aw are contiguous
    // (sizes are multiples of 256 B) -> combined B^T [96][256] / [192][256].
    ushort_t* wt_sa_off = alloc(256 * 64);
    ushort_t* wt_sa_aw  = alloc(256 * 32);
    ushort_t* wt_sa_vp  = alloc(256 * 256);
    ushort_t* wt_sa_op  = alloc(256 * 256);
    ushort_t* wt_ca_off = alloc(256 * 128);
    ushort_t* wt_ca_aw  = alloc(256 * 64);
    ushort_t* wt_ca_vp  = alloc(256 * 256);
    ushort_t* wt_ca_op  = alloc(256 * 256);
    ushort_t* wt_ffn1   = alloc(256 * 1024);
    ushort_t* wt_ffn2   = alloc(1024 * 256);
    ushort_t* qpq  = alloc(QC);     // bf16(q+pos), then bf16(q1+pos)
    ushort_t* attn = alloc(QC);     // sampled attention out; later q2 (LN2 out)
    ushort_t* q1   = alloc(QC);     // LN1 out; later FFN2 out
    ushort_t* q2   = attn;          // LN2 out overlays dead attn
    float* cb_sa_b = (float*)alloc(192);   // 96 fp32 concat bias (off++aw)
    float* cb_ca_b = (float*)alloc(384);   // 192 fp32

    TAll td;
    const float* srcs[10] = {sa_off_w, sa_aw_w, sa_vp_w, sa_op_w, ca_off_w,
                             ca_aw_w, ca_vp_w, ca_op_w, ffn_w1, ffn_w2};
    ushort_t* dsts[10] = {wt_sa_off, wt_sa_aw, wt_sa_vp, wt_sa_op, wt_ca_off,
                          wt_ca_aw, wt_ca_vp, wt_ca_op, wt_ffn1, wt_ffn2};
    int Ks[10] = {256, 256, 256, 256, 256, 256, 256, 256, 256, 1024};
    int Ns[10] = {64, 32, 256, 256, 128, 64, 256, 256, 1024, 256};
    for (int m = 0; m < 10; m++) { td.t[m] = {srcs[m], dsts[m], Ks[m], Ns[m]}; }

    // 0. prep (out_ss region is above all scratch -> safe to write early)
    prep_kernel<<<1, 192, 0, stream>>>(ss, out_ss, sa_off_b, sa_aw_b, ca_off_b, ca_aw_b,
                                       cb_sa_b, cb_ca_b);
    // 1. prologue
    prologue_kernel<<<(PRO_TOTAL + 255) / 256, 256, 0, stream>>>(query, qpos, qpq, td);

    // ---- self-attention (L=1, value = raw fp32 query) ----
    gemm_lds<64, false, 0, true, true><<<dim3(Q_ / 64, 2), 256, 0, stream>>>(
        nullptr, query, wt_sa_vp, sa_vp_b, nullptr, nullptr, vbuf, Q_, 256, 256);
    gemm_bf16<3, false, 0><<<dim3(Q_ / 256, 2), 256, 0, stream>>>(
        qpq, wt_sa_off, cb_sa_b, cqa, Q_, 96, 256);
    sample_kernel<1><<<(Q_ * NH_) / 32, 256, 0, stream>>>(vbuf, cqa, ref, attn);
    gemm_lds<64, false, 2, false, false><<<dim3(Q_ / 64, 2), 256, 0, stream>>>(
        attn, nullptr, wt_sa_op, sa_op_b, nullptr, query, tmp, Q_, 256, 256);
    ln_kernel<false><<<Q_ / 4, 256, 0, stream>>>(tmp, ln1_g, ln1_b, q1, nullptr, qpos, qpq);

    // ---- cross-attention (L=2, value = raw fp32 value) ----
    gemm_lds<64, false, 0, true, true><<<dim3(2 * Q_ / 64, 2), 256, 0, stream>>>(
        nullptr, value, wt_ca_vp, ca_vp_b, nullptr, nullptr, vbuf, 2 * Q_, 256, 256);
    gemm_bf16<3, false, 0><<<dim3(Q_ / 256, 4), 256, 0, stream>>>(
        qpq, wt_ca_off, cb_ca_b, cqa, Q_, 192, 256);
    sample_kernel<2><<<(Q_ * NH_) / 32, 256, 0, stream>>>(vbuf, cqa, ref, attn);
    gemm_lds<64, false, 1, false, false><<<dim3(Q_ / 64, 2), 256, 0, stream>>>(
        attn, nullptr, wt_ca_op, ca_op_b, q1, nullptr, tmp, Q_, 256, 256);
    ln_kernel<false><<<Q_ / 4, 256, 0, stream>>>(tmp, ln2_g, ln2_b, q2, nullptr, nullptr, nullptr);

    // ---- FFN ----
    gemm_lds<128, true, 0, false, false><<<dim3(Q_ / 128, 8), 256, 0, stream>>>(
        q2, nullptr, wt_ffn1, ffn_b1, nullptr, nullptr, hidden, Q_, 1024, 256);
    gemm_lds<64, false, 1, false, false><<<dim3(Q_ / 64, 2), 256, 0, stream>>>(
        hidden, nullptr, wt_ffn2, ffn_b2, q2, nullptr, q1, Q_, 256, 1024);
    // LN3 -> fp32 final output (overlays dead hidden region)
    ln_kernel<true><<<Q_ / 4, 256, 0, stream>>>(q1, ln3_g, ln3_b, nullptr, out_q, nullptr, nullptr);

    // ---- passthrough outputs: pure fp32 D2D copies (scratch regions now dead) ----
    hipMemcpyAsync(out_qp,  qpos,  (size_t)QC * 4,  hipMemcpyDeviceToDevice, stream);
    hipMemcpyAsync(out_val, value, (size_t)VC * 4,  hipMemcpyDeviceToDevice, stream);
    hipMemcpyAsync(out_ref, ref,   (size_t)REFN * 4, hipMemcpyDeviceToDevice, stream);

    (void)in_sizes; (void)n_in; (void)out_size; (void)ws_size;
}

// Round 11
// 489.403 us; speedup vs baseline: 1.3972x; 1.0064x over previous
//
#include <hip/hip_runtime.h>

// ---------------- problem constants ----------------
#define Q_   25600
#define C_   256
#define NH_  8
#define HD_  32
#define NP_  4
#define LC_  2
#define HW_  160          // H == W == 160

#define QC   (Q_ * C_)            // 6,553,600
#define VC   (2 * QC)             // 13,107,200
#define REFN (Q_ * LC_ * 2)       // 102,400

typedef unsigned short ushort_t;
typedef __attribute__((ext_vector_type(8))) short short8;
typedef __attribute__((ext_vector_type(4))) float f32x4;

// ---------------- bf16 helpers ----------------
__device__ __forceinline__ float b2f(ushort_t u) {
    union { unsigned int u32; float f; } c; c.u32 = ((unsigned int)u) << 16; return c.f;
}
__device__ __forceinline__ ushort_t f2b(float f) {
    union { float f; unsigned int u32; } c; c.f = f;
    unsigned int u = c.u32;
    return (ushort_t)((u + 0x7FFFu + ((u >> 16) & 1u)) >> 16);
}
__device__ __forceinline__ unsigned int pack2(float lo, float hi){
    return (unsigned int)f2b(lo) | ((unsigned int)f2b(hi) << 16);
}
__device__ __forceinline__ short8 pack8(float4 a, float4 b){
    union { short8 s; ushort_t u[8]; } r;
    r.u[0]=f2b(a.x); r.u[1]=f2b(a.y); r.u[2]=f2b(a.z); r.u[3]=f2b(a.w);
    r.u[4]=f2b(b.x); r.u[5]=f2b(b.y); r.u[6]=f2b(b.z); r.u[7]=f2b(b.w);
    return r.s;
}
__device__ __forceinline__ float uasf(unsigned int u){
    union { unsigned int u32; float f; } c; c.u32 = u; return c.f;
}
// unpack 4 bf16 (packed in uint2) -> 4 floats
__device__ __forceinline__ float4 unpk4(uint2 u){
    float4 r;
    r.x = uasf(u.x << 16); r.y = uasf(u.x & 0xFFFF0000u);
    r.z = uasf(u.y << 16); r.w = uasf(u.y & 0xFFFF0000u);
    return r;
}

// async global->LDS, 16 B per lane; LDS dest = wave-uniform base + lane*16
__device__ __forceinline__ void gload16(const void* g, void* l) {
    __builtin_amdgcn_global_load_lds(
        (const __attribute__((address_space(1))) void*)(uintptr_t)(g),
        (__attribute__((address_space(3))) void*)(uintptr_t)(l), 16, 0, 0);
}

// ---------------- prologue: qpq = bf16(query+qpos) + weight transposes (fp32->bf16)
// + (last block) ss int32->fp32 and concatenated off/aw bias vectors ----------------
struct TDesc { const float* src; ushort_t* dst; int K; int N; };
struct TAll  { TDesc t[10]; };

#define QC4   (QC / 4)        // 1,638,400
#define TRANS_TOTAL 860160
#define PRO_TOTAL (QC4 + TRANS_TOTAL)   // 2,498,560 (multiple of 256)

__global__ __launch_bounds__(256) void prologue_kernel(
    const float* __restrict__ query, const float* __restrict__ qpos,
    ushort_t* __restrict__ qpq, TAll td,
    const int* __restrict__ ss, float* __restrict__ out_ss,
    const float* __restrict__ sa_off_b, const float* __restrict__ sa_aw_b,
    const float* __restrict__ ca_off_b, const float* __restrict__ ca_aw_b,
    float* __restrict__ cb_sa, float* __restrict__ cb_ca)
{
    int i = blockIdx.x * 256 + threadIdx.x;
    if (i >= PRO_TOTAL) {
        int j = i - PRO_TOTAL;
        if (j < 4)   out_ss[j] = (float)ss[j];
        if (j < 96)  cb_sa[j] = (j < 64) ? sa_off_b[j] : sa_aw_b[j - 64];
        if (j < 192) cb_ca[j] = (j < 128) ? ca_off_b[j] : ca_aw_b[j - 128];
        return;
    }
    if (i < QC4) {
        float4 qv = ((const float4*)query)[i];
        float4 pv = ((const float4*)qpos)[i];
        uint2 o;
        o.x = pack2(qv.x + pv.x, qv.y + pv.y);
        o.y = pack2(qv.z + pv.z, qv.w + pv.w);
        ((uint2*)qpq)[i] = o;
        return;
    }
    i -= QC4;
    #pragma unroll 1
    for (int m = 0; m < 10; m++) {
        int sz = td.t[m].K * td.t[m].N;
        if (i < sz) {
            int N = td.t[m].N, K = td.t[m].K;
            int k = i / N, n = i - k * N;
            td.t[m].dst[(size_t)n * K + k] = f2b(td.t[m].src[i]);
            return;
        }
        i -= sz;
    }
}

// ---------------- LDS-staged MFMA GEMM (m97 structure, BK=64 as 2x32 sub-stages) ----------------
// C = A[M,K] @ B[K,N] + bias (+res) (+relu).  Bt = B^T [N,K] bf16.
// Tile BM x 128, 4 waves as 2x2; wave tile (BM/2) x 64.
// Per K-step (BK=64): stage both 32-col sub-tiles (linear 64B-row LDS) ->
// ONE barrier -> ds_read frags -> 2x MFMA block -> barrier.
// AF32: A staged as raw fp32, packed to bf16 on LDS read.
// RESM: 0 none, 1 bf16 residual, 2 fp32 residual.
// VOUT: write head-major value layout [(col>>5)*M + row][32].
template<int BM, bool RELU, int RESM, bool AF32, bool VOUT>
__global__ __launch_bounds__(256) void gemm_lds(
    const ushort_t* __restrict__ A16, const float* __restrict__ A32,
    const ushort_t* __restrict__ Bt, const float* __restrict__ bias,
    const ushort_t* __restrict__ res16, const float* __restrict__ res32,
    ushort_t* __restrict__ Cout, int M, int N, int K)
{
    constexpr int WM = BM / 2;                      // wave tile rows
    constexpr int MR = WM / 16;                     // A frags per wave
    constexpr int ASUB = BM * 32 * (AF32 ? 4 : 2);  // bytes per 32-col A sub-tile
    constexpr int BSUB = 128 * 32 * 2;              // bytes per 32-col B sub-tile
    __shared__ __align__(16) char smem[2 * ASUB + 2 * BSUB];
    char* lA = smem;                                // [2][BM][32] (bf16 or fp32)
    char* lB = smem + 2 * ASUB;                     // [2][128][32] bf16

    const int lane = threadIdx.x & 63;
    const int wave = threadIdx.x >> 6;
    const int wm = wave >> 1, wn = wave & 1;
    const int m0 = blockIdx.x * BM;
    const int n0 = blockIdx.y * 128;
    const int r = lane & 15, quad = lane >> 4;

    f32x4 acc[MR][4];
    #pragma unroll
    for (int i = 0; i < MR; i++)
        #pragma unroll
        for (int j = 0; j < 4; j++) acc[i][j] = (f32x4){0.f, 0.f, 0.f, 0.f};

    for (int k0 = 0; k0 < K; k0 += 64) {
        // ---- stage B: 2 sub-tiles of [128][32] bf16 (64-B rows) ----
        #pragma unroll
        for (int s = 0; s < 2; s++)
            #pragma unroll
            for (int t = 0; t < 2; t++) {
                int row = wave * 32 + t * 16;
                gload16(Bt + (size_t)(n0 + row + (lane >> 2)) * K + k0 + s * 32 + (lane & 3) * 8,
                        lB + s * BSUB + row * 64);
            }
        // ---- stage A: 2 sub-tiles ----
        if (AF32) {
            #pragma unroll
            for (int s = 0; s < 2; s++)
                #pragma unroll
                for (int t = 0; t < BM / 32; t++) {
                    int row = wave * (BM / 4) + t * 8;
                    gload16(A32 + (size_t)(m0 + row + (lane >> 3)) * K + k0 + s * 32 + (lane & 7) * 4,
                            lA + s * ASUB + row * 128);
                }
        } else {
            #pragma unroll
            for (int s = 0; s < 2; s++)
                #pragma unroll
                for (int t = 0; t < BM / 64; t++) {
                    int row = wave * (BM / 4) + t * 16;
                    gload16(A16 + (size_t)(m0 + row + (lane >> 2)) * K + k0 + s * 32 + (lane & 3) * 8,
                            lA + s * ASUB + row * 64);
                }
        }
        __syncthreads();   // compiler emits vmcnt(0) drain before the barrier

        short8 af[2][MR], bf[2][4];
        #pragma unroll
        for (int s = 0; s < 2; s++) {
            #pragma unroll
            for (int i = 0; i < MR; i++) {
                int row = wm * WM + i * 16 + r;
                if (AF32) {
                    const float* p = (const float*)(lA + s * ASUB) + row * 32 + quad * 8;
                    float4 u = *(const float4*)p;
                    float4 v = *(const float4*)(p + 4);
                    af[s][i] = pack8(u, v);
                } else {
                    af[s][i] = *(const short8*)((const ushort_t*)(lA + s * ASUB) + row * 32 + quad * 8);
                }
            }
            #pragma unroll
            for (int j = 0; j < 4; j++) {
                int row = wn * 64 + j * 16 + r;
                bf[s][j] = *(const short8*)((const ushort_t*)(lB + s * BSUB) + row * 32 + quad * 8);
            }
        }
        #pragma unroll
        for (int s = 0; s < 2; s++)
            #pragma unroll
            for (int i = 0; i < MR; i++)
                #pragma unroll
                for (int j = 0; j < 4; j++)
                    acc[i][j] = __builtin_amdgcn_mfma_f32_16x16x32_bf16(af[s][i], bf[s][j], acc[i][j], 0, 0, 0);
        __syncthreads();   // protect LDS before next-iteration stage
    }

    float bv[4];
    #pragma unroll
    for (int j = 0; j < 4; j++) bv[j] = bias[n0 + wn * 64 + j * 16 + r];

    #pragma unroll
    for (int i = 0; i < MR; i++) {
        int row = m0 + wm * WM + i * 16 + quad * 4;
        #pragma unroll
        for (int j = 0; j < 4; j++) {
            int col = n0 + wn * 64 + j * 16 + r;
            #pragma unroll
            for (int t = 0; t < 4; t++) {
                float v = acc[i][j][t] + bv[j];
                if (RESM == 1) v += b2f(res16[(size_t)(row + t) * N + col]);
                if (RESM == 2) v += res32[(size_t)(row + t) * N + col];
                if (RELU) v = fmaxf(v, 0.f);
                if (VOUT) {
                    // head-major: [(head)*M + row][32]; head = col>>5, ch = col&31
                    Cout[((size_t)(col >> 5) * (size_t)M + (size_t)(row + t)) * HD_ + (col & 31)] = f2b(v);
                } else {
                    Cout[(size_t)(row + t) * N + col] = f2b(v);
                }
            }
        }
    }
}

// ---------------- reg-direct MFMA GEMM (small-N: fused off+aw projections) ----------------
template<int WN, bool RELU, int RESM>
__global__ __launch_bounds__(256) void gemm_bf16(
    const ushort_t* __restrict__ A16,
    const ushort_t* __restrict__ Bt, const float* __restrict__ bias,
    ushort_t* __restrict__ Cout, int M, int N, int K)
{
    const int lane = threadIdx.x & 63;
    const int wave = threadIdx.x >> 6;
    const int m0 = blockIdx.x * 256 + wave * 64;
    const int n0 = blockIdx.y * (16 * WN);
    const int r = lane & 15, quad = lane >> 4;

    f32x4 acc[4][WN];
    #pragma unroll
    for (int i = 0; i < 4; i++)
        #pragma unroll
        for (int j = 0; j < WN; j++) acc[i][j] = (f32x4){0.f, 0.f, 0.f, 0.f};

    const ushort_t* Ab16 = A16 + (size_t)(m0 + r) * K + quad * 8;
    const ushort_t* Bbase = Bt + (size_t)(n0 + r) * K + quad * 8;

    for (int k0 = 0; k0 < K; k0 += 64) {
        short8 af0[4], af1[4], b0[WN], b1[WN];
        #pragma unroll
        for (int i = 0; i < 4; i++) {
            af0[i] = *(const short8*)(Ab16 + (size_t)i * 16 * K + k0);
            af1[i] = *(const short8*)(Ab16 + (size_t)i * 16 * K + k0 + 32);
        }
        #pragma unroll
        for (int j = 0; j < WN; j++) {
            b0[j] = *(const short8*)(Bbase + (size_t)j * 16 * K + k0);
            b1[j] = *(const short8*)(Bbase + (size_t)j * 16 * K + k0 + 32);
        }
        #pragma unroll
        for (int i = 0; i < 4; i++)
            #pragma unroll
            for (int j = 0; j < WN; j++)
                acc[i][j] = __builtin_amdgcn_mfma_f32_16x16x32_bf16(af0[i], b0[j], acc[i][j], 0, 0, 0);
        #pragma unroll
        for (int i = 0; i < 4; i++)
            #pragma unroll
            for (int j = 0; j < WN; j++)
                acc[i][j] = __builtin_amdgcn_mfma_f32_16x16x32_bf16(af1[i], b1[j], acc[i][j], 0, 0, 0);
    }

    float bv[WN];
    #pragma unroll
    for (int j = 0; j < WN; j++) bv[j] = bias[n0 + j * 16 + r];

    #pragma unroll
    for (int i = 0; i < 4; i++) {
        int row = m0 + i * 16 + quad * 4;
        #pragma unroll
        for (int j = 0; j < WN; j++) {
            int col = n0 + j * 16 + r;
            #pragma unroll
            for (int t = 0; t < 4; t++) {
                float v = acc[i][j][t] + bv[j];
                if (RELU) v = fmaxf(v, 0.f);
                Cout[(size_t)(row + t) * N + col] = f2b(v);
            }
        }
    }
}

// ---------------- fused softmax + bilinear sampling (+ optional passthrough copy) ----------------
// v layout: [(h*L + l)*Q + pix][HD]  (head-major, 64 B per pixel record)
// cb: combined [Q][off(NH*P*2) ++ aw(NH*P)] bf16 from the fused projection GEMM.
// 8 lanes per (q,h) group; each lane owns 4 channels (uint2 corner loads).
// cpsrc/cpdst: grid-stride float4 copy (cpn float4s) folded in -- uses the
// latency-bound kernel's spare HBM bandwidth for passthrough outputs.
template<int L>
__global__ __launch_bounds__(256) void sample_kernel(
    const ushort_t* __restrict__ v,    // head-major projected value (bf16)
    const ushort_t* __restrict__ cb,   // [Q, NH*L*NP*3] combined off+aw (bf16)
    const float*    __restrict__ ref,  // [Q, LC, 2] fp32
    ushort_t* __restrict__ outp,       // [Q, C] bf16
    const float4* __restrict__ cpsrc, float4* __restrict__ cpdst, int cpn)
{
    const int t   = blockIdx.x * 256 + threadIdx.x;
    const int g   = t >> 3;            // (q,h) group
    const int sub = t & 7;             // 4-channel slice within head
    const int q   = g >> 3;
    const int h   = g & 7;
    const int P   = L * NP_;
    const int STR = NH_ * P * 3;       // 96 (L=1) or 192 (L=2)

    // ---- softmax over P logits (vectorized bf16 load, normalized in-place) ----
    float w[2 * NP_];
    {
        union { uint4 q4; uint2 q2; ushort_t u[8]; } ab;
        const ushort_t* awp = cb + (size_t)q * STR + NH_ * P * 2 + h * P;
        if (L == 2) ab.q4 = *(const uint4*)awp;
        else        ab.q2 = *(const uint2*)awp;
        float mx = -1e30f;
        #pragma unroll
        for (int i = 0; i < P; i++) { w[i] = b2f(ab.u[i]); mx = fmaxf(mx, w[i]); }
        float s = 0.f;
        #pragma unroll
        for (int i = 0; i < P; i++) { w[i] = __expf(w[i] - mx); s += w[i]; }
        float inv = 1.f / s;
        #pragma unroll
        for (int i = 0; i < P; i++) w[i] *= inv;
    }

    // ---- offsets (vectorized bf16 load) ----
    float offx[2 * NP_], offy[2 * NP_];
    {
        union { uint4 q4[2]; ushort_t u[16]; } ob;
        const ushort_t* offp = cb + (size_t)q * STR + h * (P * 2);
        ob.q4[0] = *(const uint4*)offp;
        if (L == 2) ob.q4[1] = *(const uint4*)(offp + 8);
        #pragma unroll
        for (int i = 0; i < P; i++) { offx[i] = b2f(ob.u[2 * i]); offy[i] = b2f(ob.u[2 * i + 1]); }
    }

    const ushort_t* vh = v + ((size_t)(h * L) * Q_) * HD_ + sub * 4;
    float4 acc = {0.f, 0.f, 0.f, 0.f};

    #pragma unroll
    for (int l = 0; l < L; l++) {
        float rx = ref[((size_t)q * LC_ + l) * 2 + 0] * (float)HW_ - 0.5f;
        float ry = ref[((size_t)q * LC_ + l) * 2 + 1] * (float)HW_ - 0.5f;
        const ushort_t* vl = vh + (size_t)l * ((size_t)Q_ * HD_);
        #pragma unroll
        for (int p = 0; p < NP_; p++) {
            const int ip = l * NP_ + p;
            float x = rx + offx[ip];
            float y = ry + offy[ip];
            x = fminf(fmaxf(x, -1e4f), 1e4f);
            y = fminf(fmaxf(y, -1e4f), 1e4f);
            float xf = floorf(x), yf = floorf(y);
            float tx = x - xf, ty = y - yf;
            int x0 = (int)xf, y0 = (int)yf;
            int x1 = x0 + 1, y1 = y0 + 1;
            int xc0 = min(max(x0, 0), HW_ - 1), xc1 = min(max(x1, 0), HW_ - 1);
            int yc0 = min(max(y0, 0), HW_ - 1), yc1 = min(max(y1, 0), HW_ - 1);
            bool vx0 = (unsigned)x0 < (unsigned)HW_, vx1 = (unsigned)x1 < (unsigned)HW_;
            bool vy0 = (unsigned)y0 < (unsigned)HW_, vy1 = (unsigned)y1 < (unsigned)HW_;

            // fold attention weight + validity into the 4 corner weights
            float aww = w[ip];
            float w00 = (1.f - tx) * (1.f - ty) * aww;
            float w10 = tx * (1.f - ty) * aww;
            float w01 = (1.f - tx) * ty * aww;
            float w11 = tx * ty * aww;
            w00 = (vx0 & vy0) ? w00 : 0.f;
            w10 = (vx1 & vy0) ? w10 : 0.f;
            w01 = (vx0 & vy1) ? w01 : 0.f;
            w11 = (vx1 & vy1) ? w11 : 0.f;

            int r0 = yc0 * HW_, r1 = yc1 * HW_;
            uint2 u00 = *(const uint2*)(vl + (size_t)(r0 + xc0) * HD_);
            uint2 u10 = *(const uint2*)(vl + (size_t)(r0 + xc1) * HD_);
            uint2 u01 = *(const uint2*)(vl + (size_t)(r1 + xc0) * HD_);
            uint2 u11 = *(const uint2*)(vl + (size_t)(r1 + xc1) * HD_);
            float4 c00 = unpk4(u00), c10 = unpk4(u10), c01 = unpk4(u01), c11 = unpk4(u11);

            acc.x += c00.x * w00 + c10.x * w10 + c01.x * w01 + c11.x * w11;
            acc.y += c00.y * w00 + c10.y * w10 + c01.y * w01 + c11.y * w11;
            acc.z += c00.z * w00 + c10.z * w10 + c01.z * w01 + c11.z * w11;
            acc.w += c00.w * w00 + c10.w * w10 + c01.w * w01 + c11.w * w11;
        }
    }

    uint2 o;
    o.x = pack2(acc.x, acc.y);
    o.y = pack2(acc.z, acc.w);
    *(uint2*)(outp + (size_t)q * C_ + h * HD_ + sub * 4) = o;

    // ---- folded passthrough copy (grid-stride float4) ----
    if (cpdst) {
        const int nt = gridDim.x * 256;
        for (int i = t; i < cpn; i += nt) cpdst[i] = cpsrc[i];
    }
}

// ---------------- LayerNorm (wave per row of 256) ----------------
// x bf16; gamma/beta fp32. OUT32: y32 fp32 out, else y16 bf16 out.
// optional y2 (bf16) = y + qpos (qpos fp32).
// optional cpsrc/cpdst: one float4 passthrough-copy per thread (grid size
// must equal copy size / 4 floats) -- used by LN3 for out_qp.
template<bool OUT32>
__global__ __launch_bounds__(256) void ln_kernel(
    const ushort_t* __restrict__ x, const float* __restrict__ g,
    const float* __restrict__ b, ushort_t* __restrict__ y16,
    float* __restrict__ y32,
    const float* __restrict__ qpos, ushort_t* __restrict__ y2,
    const float4* __restrict__ cpsrc, float4* __restrict__ cpdst)
{
    const int lane = threadIdx.x & 63;
    const int wave = threadIdx.x >> 6;
    const size_t row = (size_t)blockIdx.x * 4 + wave;
    const size_t base = row * C_ + lane * 4;

    uint2 xv = *(const uint2*)(x + base);
    float f0 = b2f((ushort_t)(xv.x & 0xFFFF)), f1 = b2f((ushort_t)(xv.x >> 16));
    float f2 = b2f((ushort_t)(xv.y & 0xFFFF)), f3 = b2f((ushort_t)(xv.y >> 16));
    float s  = f0 + f1 + f2 + f3;
    float sq = f0 * f0 + f1 * f1 + f2 * f2 + f3 * f3;
    #pragma unroll
    for (int m = 1; m < 64; m <<= 1) { s += __shfl_xor(s, m, 64); sq += __shfl_xor(sq, m, 64); }
    float mean = s * (1.f / 256.f);
    float var  = sq * (1.f / 256.f) - mean * mean;
    float rinv = rsqrtf(fmaxf(var, 0.f) + 1e-5f);

    float4 gv = *(const float4*)(g + lane * 4);
    float4 bv = *(const float4*)(b + lane * 4);
    float o0 = (f0 - mean) * rinv * gv.x + bv.x;
    float o1 = (f1 - mean) * rinv * gv.y + bv.y;
    float o2 = (f2 - mean) * rinv * gv.z + bv.z;
    float o3 = (f3 - mean) * rinv * gv.w + bv.w;

    if (OUT32) {
        float4 o; o.x = o0; o.y = o1; o.z = o2; o.w = o3;
        *(float4*)(y32 + base) = o;
    } else {
        uint2 ov; ov.x = pack2(o0, o1); ov.y = pack2(o2, o3);
        *(uint2*)(y16 + base) = ov;
    }

    if (y2) {
        float4 pv = *(const float4*)(qpos + base);
        uint2 o2v;
        o2v.x = pack2(o0 + pv.x, o1 + pv.y);
        o2v.y = pack2(o2 + pv.z, o3 + pv.w);
        *(uint2*)(y2 + base) = o2v;
    }

    if (cpdst) {
        int tid = blockIdx.x * 256 + threadIdx.x;
        cpdst[tid] = cpsrc[tid];
    }
}

// ---------------- host ----------------
extern "C" void kernel_launch(void* const* d_in, const int* in_sizes, int n_in,
                              void* d_out, int out_size, void* d_ws, size_t ws_size,
                              hipStream_t stream)
{
    const float* query = (const float*)d_in[0];
    const float* qpos  = (const float*)d_in[1];
    const float* value = (const float*)d_in[2];
    const float* ref   = (const float*)d_in[3];
    const int*   ss    = (const int*)d_in[4];
    const float* sa_off_w = (const float*)d_in[5];
    const float* sa_off_b = (const float*)d_in[6];
    const float* sa_aw_w  = (const float*)d_in[7];
    const float* sa_aw_b  = (const float*)d_in[8];
    const float* sa_vp_w  = (const float*)d_in[9];
    const float* sa_vp_b  = (const float*)d_in[10];
    const float* sa_op_w  = (const float*)d_in[11];
    const float* sa_op_b  = (const float*)d_in[12];
    const float* ca_off_w = (const float*)d_in[13];
    const float* ca_off_b = (const float*)d_in[14];
    const float* ca_aw_w  = (const float*)d_in[15];
    const float* ca_aw_b  = (const float*)d_in[16];
    const float* ca_vp_w  = (const float*)d_in[17];
    const float* ca_vp_b  = (const float*)d_in[18];
    const float* ca_op_w  = (const float*)d_in[19];
    const float* ca_op_b  = (const float*)d_in[20];
    const float* ffn_w1   = (const float*)d_in[21];
    const float* ffn_b1   = (const float*)d_in[22];
    const float* ffn_w2   = (const float*)d_in[23];
    const float* ffn_b2   = (const float*)d_in[24];
    const float* ln1_g = (const float*)d_in[25];
    const float* ln1_b = (const float*)d_in[26];
    const float* ln2_g = (const float*)d_in[27];
    const float* ln2_b = (const float*)d_in[28];
    const float* ln3_g = (const float*)d_in[29];
    const float* ln3_b = (const float*)d_in[30];

    // ---- final output layout (fp32) ----
    float* outf    = (float*)d_out;
    float* out_q   = outf;                            // [Q,C]   bytes [0, 26.2M)
    float* out_qp  = outf + QC;                       // [Q,C]   bytes [26.2M, 52.4M)
    float* out_val = outf + 2 * (size_t)QC;           // [2Q,C]  bytes [52.4M, 104.9M)
    float* out_ref = outf + 4 * (size_t)QC;           // [Q,LC,2] bytes [104.9M, 105.3M)
    float* out_ss  = outf + 4 * (size_t)QC + REFN;    // [4]

    // ---- d_out doubles as bf16 body scratch; all scratch lives in bytes [0, 52.4M) ----
    // out_val / out_ref / out_ss regions are NEVER scratch -> safe to fill early.
    // out_qp region overlaps tmp/cqa/hidden -> filled by LN3 (after FFN2).
    ushort_t* dsc    = (ushort_t*)d_out;
    ushort_t* vbuf   = dsc;                           // 2QC bf16 (head-major value)
    ushort_t* tmp    = dsc + 2 * (size_t)QC;          // QC bf16
    ushort_t* cqa    = dsc + 3 * (size_t)QC;          // Q*192 bf16 max (combined off+aw)
    ushort_t* hidden = dsc;                           // Q*1024 bf16

    // ---- workspace: ~42.8 MB bf16 ----
    char* base = (char*)d_ws;
    size_t offbyte = 0;
    auto alloc = [&](size_t elems) -> ushort_t* {
        ushort_t* p = (ushort_t*)(base + offbyte);
        offbyte += ((elems * 2 + 255) / 256) * 256;
        return p;
    };
    // NOTE: wt_sa_off/wt_sa_aw and wt_ca_off/wt_ca_aw are contiguous
    // (sizes are multiples of 256 B) -> combined B^T [96][256] / [192][256].
    ushort_t* wt_sa_off = alloc(256 * 64);
    ushort_t* wt_sa_aw  = alloc(256 * 32);
    ushort_t* wt_sa_vp  = alloc(256 * 256);
    ushort_t* wt_sa_op  = alloc(256 * 256);
    ushort_t* wt_ca_off = alloc(256 * 128);
    ushort_t* wt_ca_aw  = alloc(256 * 64);
    ushort_t* wt_ca_vp  = alloc(256 * 256);
    ushort_t* wt_ca_op  = alloc(256 * 256);
    ushort_t* wt_ffn1   = alloc(256 * 1024);
    ushort_t* wt_ffn2   = alloc(1024 * 256);
    ushort_t* qpq  = alloc(QC);     // bf16(q+pos), then bf16(q1+pos)
    ushort_t* attn = alloc(QC);     // sampled attention out; later q2 (LN2 out)
    ushort_t* q1   = alloc(QC);     // LN1 out; later FFN2 out
    ushort_t* q2   = attn;          // LN2 out overlays dead attn
    float* cb_sa_b = (float*)alloc(192);   // 96 fp32 concat bias (off++aw)
    float* cb_ca_b = (float*)alloc(384);   // 192 fp32

    TAll td;
    const float* srcs[10] = {sa_off_w, sa_aw_w, sa_vp_w, sa_op_w, ca_off_w,
                             ca_aw_w, ca_vp_w, ca_op_w, ffn_w1, ffn_w2};
    ushort_t* dsts[10] = {wt_sa_off, wt_sa_aw, wt_sa_vp, wt_sa_op, wt_ca_off,
                          wt_ca_aw, wt_ca_vp, wt_ca_op, wt_ffn1, wt_ffn2};
    int Ks[10] = {256, 256, 256, 256, 256, 256, 256, 256, 256, 1024};
    int Ns[10] = {64, 32, 256, 256, 128, 64, 256, 256, 1024, 256};
    for (int m = 0; m < 10; m++) { td.t[m] = {srcs[m], dsts[m], Ks[m], Ns[m]}; }

    // 1. prologue (+1 block: ss->fp32 + concat bias vectors)
    prologue_kernel<<<PRO_TOTAL / 256 + 1, 256, 0, stream>>>(
        query, qpos, qpq, td, ss, out_ss,
        sa_off_b, sa_aw_b, ca_off_b, ca_aw_b, cb_sa_b, cb_ca_b);

    // ---- self-attention (L=1, value = raw fp32 query) ----
    gemm_lds<64, false, 0, true, true><<<dim3(Q_ / 64, 2), 256, 0, stream>>>(
        nullptr, query, wt_sa_vp, sa_vp_b, nullptr, nullptr, vbuf, Q_, 256, 256);
    gemm_bf16<3, false, 0><<<dim3(Q_ / 256, 2), 256, 0, stream>>>(
        qpq, wt_sa_off, cb_sa_b, cqa, Q_, 96, 256);
    // + folded out_ref copy (REFN floats = REFN/4 float4s)
    sample_kernel<1><<<(Q_ * NH_) / 32, 256, 0, stream>>>(
        vbuf, cqa, ref, attn, (const float4*)ref, (float4*)out_ref, REFN / 4);
    gemm_lds<64, false, 2, false, false><<<dim3(Q_ / 64, 2), 256, 0, stream>>>(
        attn, nullptr, wt_sa_op, sa_op_b, nullptr, query, tmp, Q_, 256, 256);
    ln_kernel<false><<<Q_ / 4, 256, 0, stream>>>(
        tmp, ln1_g, ln1_b, q1, nullptr, qpos, qpq, nullptr, nullptr);

    // ---- cross-attention (L=2, value = raw fp32 value) ----
    gemm_lds<64, false, 0, true, true><<<dim3(2 * Q_ / 64, 2), 256, 0, stream>>>(
        nullptr, value, wt_ca_vp, ca_vp_b, nullptr, nullptr, vbuf, 2 * Q_, 256, 256);
    gemm_bf16<3, false, 0><<<dim3(Q_ / 256, 4), 256, 0, stream>>>(
        qpq, wt_ca_off, cb_ca_b, cqa, Q_, 192, 256);
    // + folded out_val copy (VC floats = VC/4 float4s; ~2 per thread grid-stride)
    sample_kernel<2><<<(Q_ * NH_) / 32, 256, 0, stream>>>(
        vbuf, cqa, ref, attn, (const float4*)value, (float4*)out_val, VC / 4);
    gemm_lds<64, false, 1, false, false><<<dim3(Q_ / 64, 2), 256, 0, stream>>>(
        attn, nullptr, wt_ca_op, ca_op_b, q1, nullptr, tmp, Q_, 256, 256);
    ln_kernel<false><<<Q_ / 4, 256, 0, stream>>>(
        tmp, ln2_g, ln2_b, q2, nullptr, nullptr, nullptr, nullptr, nullptr);

    // ---- FFN ----
    gemm_lds<128, true, 0, false, false><<<dim3(Q_ / 128, 8), 256, 0, stream>>>(
        q2, nullptr, wt_ffn1, ffn_b1, nullptr, nullptr, hidden, Q_, 1024, 256);
    gemm_lds<64, false, 1, false, false><<<dim3(Q_ / 64, 2), 256, 0, stream>>>(
        hidden, nullptr, wt_ffn2, ffn_b2, q2, nullptr, q1, Q_, 256, 1024);
    // LN3 -> fp32 final output; + folded out_qp copy (hidden/tmp/cqa all dead now;
    // grid 6400*256 threads == QC/4 float4s exactly -> 1 per thread)
    ln_kernel<true><<<Q_ / 4, 256, 0, stream>>>(
        q1, ln3_g, ln3_b, nullptr, out_q, nullptr, nullptr,
        (const float4*)qpos, (float4*)out_qp);

    (void)in_sizes; (void)n_in; (void)out_size; (void)ws_size;
}